// Round 9
// baseline (928.623 us; speedup 1.0000x reference)
//
#include <hip/hip_runtime.h>
#include <math.h>

// Problem constants
#define B 64
#define NN 49
#define ENC 2048
#define DEC 512
#define ATT 512
#define EMB 300
#define VOC 10000
#define TT 30

typedef __attribute__((ext_vector_type(4))) float f32x4;
typedef __attribute__((ext_vector_type(4))) short s16x4;
typedef __attribute__((ext_vector_type(8))) short s16x8;
typedef unsigned short u16;

__device__ __forceinline__ float fast_tanh(float x) {
    float e = __expf(2.f * x);
    return 1.f - 2.f / (e + 1.f);
}
__device__ __forceinline__ float sigmoidf(float x) {
    return 1.f / (1.f + __expf(-x));
}
__device__ __forceinline__ u16 f2bf(float x) {
    unsigned u = __float_as_uint(x);
    unsigned r = u + 0x7FFFu + ((u >> 16) & 1u);
    return (u16)(r >> 16);
}
__device__ __forceinline__ float bf2f(u16 u) {
    return __uint_as_float((unsigned)u << 16);
}
__device__ __forceinline__ void split_bf16(float x, short& hi, short& lo) {
    u16 h = f2bf(x);
    float hf = __uint_as_float((unsigned)h << 16);
    hi = (short)h;
    lo = (short)f2bf(x - hf);
}
__device__ __forceinline__ s16x8 ld8(const short* p) {
    s16x4 a = *(const s16x4*)p;
    s16x4 b = *(const s16x4*)(p + 4);
    return __builtin_shufflevector(a, b, 0, 1, 2, 3, 4, 5, 6, 7);
}

// ---------------------------------------------------------------------------
// mfma_cat2: A = pre-split features (hi/lo), B = [U_w (on-the-fly) ;
// pre-split ih_w slice]. K=2048, N=2560. col<512 -> uhs16 (+U_b), else fW16.
// ---------------------------------------------------------------------------
__global__ __launch_bounds__(512) void mfma_cat2(
    const u16* __restrict__ fhi, const u16* __restrict__ flo,
    const float* __restrict__ U_w, const float* __restrict__ U_b,
    const u16* __restrict__ ihw_h, const u16* __restrict__ ihw_l,
    u16* __restrict__ uhs16, u16* __restrict__ fW16, int M)
{
    __shared__ short Ah[128][40];
    __shared__ short Al[128][40];
    __shared__ short Bh[128][40];
    __shared__ short Bl[128][40];

    const int tid = threadIdx.x;
    const int m0 = blockIdx.y * 128, n0 = blockIdx.x * 128;
    const int wid = tid >> 6, lane = tid & 63;
    const int wm = wid >> 2, wn = wid & 3;
    const int lrow = lane & 15;
    const int lko = (lane >> 4) * 8;
    const int srow = tid >> 2;
    const int sk = (tid & 3) * 8;

    const int gc = n0 + srow;
    const int gr = m0 + srow;
    const u16* ahp = fhi + (size_t)gr * 2048;
    const u16* alp = flo + (size_t)gr * 2048;

    f32x4 acc[4][2];
    #pragma unroll
    for (int i = 0; i < 4; ++i)
        #pragma unroll
        for (int j = 0; j < 2; ++j)
            acc[i][j] = (f32x4){0.f, 0.f, 0.f, 0.f};

    for (int kt = 0; kt < 64; ++kt) {
        const int kb0 = kt * 32 + sk;
        {
            s16x8 vh = {0,0,0,0,0,0,0,0}, vl = {0,0,0,0,0,0,0,0};
            if (gr < M) {
                vh = *(const s16x8*)(ahp + kb0);
                vl = *(const s16x8*)(alp + kb0);
            }
            *(s16x8*)&Ah[srow][sk] = vh;
            *(s16x8*)&Al[srow][sk] = vl;
        }
        if (n0 < 512) {   // U_w columns: split on the fly (uniform per block)
            const float* bp = U_w + (size_t)gc * 2048;
            float4 x0 = *(const float4*)(bp + kb0);
            float4 x1 = *(const float4*)(bp + kb0 + 4);
            float v[8] = {x0.x, x0.y, x0.z, x0.w, x1.x, x1.y, x1.z, x1.w};
            s16x4 h0, h1, l0, l1;
            #pragma unroll
            for (int j = 0; j < 4; ++j) { short h, l; split_bf16(v[j], h, l); h0[j] = h; l0[j] = l; }
            #pragma unroll
            for (int j = 0; j < 4; ++j) { short h, l; split_bf16(v[4 + j], h, l); h1[j] = h; l1[j] = l; }
            *(s16x4*)&Bh[srow][sk] = h0; *(s16x4*)&Bh[srow][sk + 4] = h1;
            *(s16x4*)&Bl[srow][sk] = l0; *(s16x4*)&Bl[srow][sk + 4] = l1;
        } else {          // pre-split ih_w columns
            *(s16x8*)&Bh[srow][sk] = *(const s16x8*)(ihw_h + (size_t)(gc - 512) * 2048 + kb0);
            *(s16x8*)&Bl[srow][sk] = *(const s16x8*)(ihw_l + (size_t)(gc - 512) * 2048 + kb0);
        }
        __syncthreads();

        s16x8 bh[2], bl[2];
        #pragma unroll
        for (int nr = 0; nr < 2; ++nr) {
            const int col = wn * 32 + nr * 16 + lrow;
            bh[nr] = ld8(&Bh[col][lko]);
            bl[nr] = ld8(&Bl[col][lko]);
        }
        #pragma unroll
        for (int mr = 0; mr < 4; ++mr) {
            const int row = wm * 64 + mr * 16 + lrow;
            s16x8 ah = ld8(&Ah[row][lko]);
            s16x8 al = ld8(&Al[row][lko]);
            #pragma unroll
            for (int nr = 0; nr < 2; ++nr) {
                acc[mr][nr] = __builtin_amdgcn_mfma_f32_16x16x32_bf16(ah, bh[nr], acc[mr][nr], 0, 0, 0);
                acc[mr][nr] = __builtin_amdgcn_mfma_f32_16x16x32_bf16(ah, bl[nr], acc[mr][nr], 0, 0, 0);
                acc[mr][nr] = __builtin_amdgcn_mfma_f32_16x16x32_bf16(al, bh[nr], acc[mr][nr], 0, 0, 0);
            }
        }
        __syncthreads();
    }

    #pragma unroll
    for (int mr = 0; mr < 4; ++mr) {
        #pragma unroll
        for (int nr = 0; nr < 2; ++nr) {
            #pragma unroll
            for (int r = 0; r < 4; ++r) {
                const int row = m0 + wm * 64 + mr * 16 + (lane >> 4) * 4 + r;
                const int col = n0 + wn * 32 + nr * 16 + (lane & 15);
                if (row < M) {
                    if (col < 512)
                        uhs16[(size_t)row * 512 + col] = f2bf(acc[mr][nr][r] + U_b[col]);
                    else
                        fW16[(size_t)row * 2048 + (col - 512)] = f2bf(acc[mr][nr][r]);
                }
            }
        }
    }
}

// ---------------------------------------------------------------------------
// mfma_prex: pre_x = gather(emb, captions) @ ih_w[:, :300]^T + bias2.
// M=1920 (row = t*64+b), N=2048, K=300. A rows gathered via captions.
// ---------------------------------------------------------------------------
__global__ __launch_bounds__(512) void mfma_prex(
    const int* __restrict__ cap,
    const float* __restrict__ emb,
    const float* __restrict__ ih_w,
    const float* __restrict__ bias2,
    float* __restrict__ pre_x)
{
    __shared__ short Ah[128][40];
    __shared__ short Al[128][40];
    __shared__ short Bh[128][40];
    __shared__ short Bl[128][40];

    const int tid = threadIdx.x;
    const int m0 = blockIdx.y * 128, n0 = blockIdx.x * 128;
    const int wid = tid >> 6, lane = tid & 63;
    const int wm = wid >> 2, wn = wid & 3;
    const int lrow = lane & 15;
    const int lko = (lane >> 4) * 8;
    const int srow = tid >> 2;
    const int sk = (tid & 3) * 8;

    const int gr = m0 + srow;                       // < 1920 always
    const int tt = gr >> 6, bbs = gr & 63;
    const float* ap = emb + (size_t)cap[bbs * 31 + tt] * 300;
    const int gc = n0 + srow;                       // < 2048 always
    const float* bp = ih_w + (size_t)gc * 2348;

    f32x4 acc[4][2];
    #pragma unroll
    for (int i = 0; i < 4; ++i)
        #pragma unroll
        for (int j = 0; j < 2; ++j)
            acc[i][j] = (f32x4){0.f, 0.f, 0.f, 0.f};

    for (int kt = 0; kt < 10; ++kt) {
        const int kb0 = kt * 32 + sk;
        {
            float v[8];
            if (kb0 + 7 < 300) {
                float4 x0 = *(const float4*)(ap + kb0);
                float4 x1 = *(const float4*)(ap + kb0 + 4);
                v[0] = x0.x; v[1] = x0.y; v[2] = x0.z; v[3] = x0.w;
                v[4] = x1.x; v[5] = x1.y; v[6] = x1.z; v[7] = x1.w;
            } else {
                #pragma unroll
                for (int j = 0; j < 8; ++j)
                    v[j] = (kb0 + j < 300) ? ap[kb0 + j] : 0.f;
            }
            s16x4 h0, h1, l0, l1;
            #pragma unroll
            for (int j = 0; j < 4; ++j) { short h, l; split_bf16(v[j], h, l); h0[j] = h; l0[j] = l; }
            #pragma unroll
            for (int j = 0; j < 4; ++j) { short h, l; split_bf16(v[4 + j], h, l); h1[j] = h; l1[j] = l; }
            *(s16x4*)&Ah[srow][sk] = h0; *(s16x4*)&Ah[srow][sk + 4] = h1;
            *(s16x4*)&Al[srow][sk] = l0; *(s16x4*)&Al[srow][sk + 4] = l1;
        }
        {
            float v[8];
            if (kb0 + 7 < 300) {
                float4 x0 = *(const float4*)(bp + kb0);
                float4 x1 = *(const float4*)(bp + kb0 + 4);
                v[0] = x0.x; v[1] = x0.y; v[2] = x0.z; v[3] = x0.w;
                v[4] = x1.x; v[5] = x1.y; v[6] = x1.z; v[7] = x1.w;
            } else {
                #pragma unroll
                for (int j = 0; j < 8; ++j)
                    v[j] = (kb0 + j < 300) ? bp[kb0 + j] : 0.f;
            }
            s16x4 h0, h1, l0, l1;
            #pragma unroll
            for (int j = 0; j < 4; ++j) { short h, l; split_bf16(v[j], h, l); h0[j] = h; l0[j] = l; }
            #pragma unroll
            for (int j = 0; j < 4; ++j) { short h, l; split_bf16(v[4 + j], h, l); h1[j] = h; l1[j] = l; }
            *(s16x4*)&Bh[srow][sk] = h0; *(s16x4*)&Bh[srow][sk + 4] = h1;
            *(s16x4*)&Bl[srow][sk] = l0; *(s16x4*)&Bl[srow][sk + 4] = l1;
        }
        __syncthreads();

        s16x8 bh[2], bl[2];
        #pragma unroll
        for (int nr = 0; nr < 2; ++nr) {
            const int col = wn * 32 + nr * 16 + lrow;
            bh[nr] = ld8(&Bh[col][lko]);
            bl[nr] = ld8(&Bl[col][lko]);
        }
        #pragma unroll
        for (int mr = 0; mr < 4; ++mr) {
            const int row = wm * 64 + mr * 16 + lrow;
            s16x8 ah = ld8(&Ah[row][lko]);
            s16x8 al = ld8(&Al[row][lko]);
            #pragma unroll
            for (int nr = 0; nr < 2; ++nr) {
                acc[mr][nr] = __builtin_amdgcn_mfma_f32_16x16x32_bf16(ah, bh[nr], acc[mr][nr], 0, 0, 0);
                acc[mr][nr] = __builtin_amdgcn_mfma_f32_16x16x32_bf16(ah, bl[nr], acc[mr][nr], 0, 0, 0);
                acc[mr][nr] = __builtin_amdgcn_mfma_f32_16x16x32_bf16(al, bh[nr], acc[mr][nr], 0, 0, 0);
            }
        }
        __syncthreads();
    }

    #pragma unroll
    for (int mr = 0; mr < 4; ++mr) {
        #pragma unroll
        for (int nr = 0; nr < 2; ++nr) {
            #pragma unroll
            for (int r = 0; r < 4; ++r) {
                const int row = m0 + wm * 64 + mr * 16 + (lane >> 4) * 4 + r;
                const int col = n0 + wn * 32 + nr * 16 + (lane & 15);
                pre_x[(size_t)row * 2048 + col] = acc[mr][nr][r] + bias2[col];
            }
        }
    }
}

// ---------------------------------------------------------------------------
// Pre-split bf16 MFMA GEMM: K=512, preds scatter + bias.
// ---------------------------------------------------------------------------
__global__ __launch_bounds__(512) void mfma_pre(
    const u16* __restrict__ Ahg, const u16* __restrict__ Alg,
    const u16* __restrict__ Bhg, const u16* __restrict__ Blg,
    const float* __restrict__ bias,
    float* __restrict__ C, int M, int N)
{
    __shared__ short Ah[128][40];
    __shared__ short Al[128][40];
    __shared__ short Bh[128][40];
    __shared__ short Bl[128][40];

    const int tid = threadIdx.x;
    const int m0 = blockIdx.y * 128, n0 = blockIdx.x * 128;
    const int wid = tid >> 6, lane = tid & 63;
    const int wm = wid >> 2, wn = wid & 3;
    const int lrow = lane & 15;
    const int lko = (lane >> 4) * 8;
    const int srow = tid >> 2;
    const int sk = (tid & 3) * 8;

    f32x4 acc[4][2];
    #pragma unroll
    for (int i = 0; i < 4; ++i)
        #pragma unroll
        for (int j = 0; j < 2; ++j)
            acc[i][j] = (f32x4){0.f, 0.f, 0.f, 0.f};

    for (int kt = 0; kt < 16; ++kt) {
        const int kb0 = kt * 32 + sk;
        {
            const int gr = m0 + srow;
            s16x8 vh = {0,0,0,0,0,0,0,0}, vl = {0,0,0,0,0,0,0,0};
            if (gr < M) {
                vh = *(const s16x8*)(Ahg + (size_t)gr * 512 + kb0);
                vl = *(const s16x8*)(Alg + (size_t)gr * 512 + kb0);
            }
            *(s16x8*)&Ah[srow][sk] = vh;
            *(s16x8*)&Al[srow][sk] = vl;
        }
        {
            const int gc = n0 + srow;
            s16x8 vh = {0,0,0,0,0,0,0,0}, vl = {0,0,0,0,0,0,0,0};
            if (gc < N) {
                vh = *(const s16x8*)(Bhg + (size_t)gc * 512 + kb0);
                vl = *(const s16x8*)(Blg + (size_t)gc * 512 + kb0);
            }
            *(s16x8*)&Bh[srow][sk] = vh;
            *(s16x8*)&Bl[srow][sk] = vl;
        }
        __syncthreads();

        s16x8 bh[2], bl[2];
        #pragma unroll
        for (int nr = 0; nr < 2; ++nr) {
            const int col = wn * 32 + nr * 16 + lrow;
            bh[nr] = ld8(&Bh[col][lko]);
            bl[nr] = ld8(&Bl[col][lko]);
        }
        #pragma unroll
        for (int mr = 0; mr < 4; ++mr) {
            const int row = wm * 64 + mr * 16 + lrow;
            s16x8 ah = ld8(&Ah[row][lko]);
            s16x8 al = ld8(&Al[row][lko]);
            #pragma unroll
            for (int nr = 0; nr < 2; ++nr) {
                acc[mr][nr] = __builtin_amdgcn_mfma_f32_16x16x32_bf16(ah, bh[nr], acc[mr][nr], 0, 0, 0);
                acc[mr][nr] = __builtin_amdgcn_mfma_f32_16x16x32_bf16(ah, bl[nr], acc[mr][nr], 0, 0, 0);
                acc[mr][nr] = __builtin_amdgcn_mfma_f32_16x16x32_bf16(al, bh[nr], acc[mr][nr], 0, 0, 0);
            }
        }
        __syncthreads();
    }

    #pragma unroll
    for (int mr = 0; mr < 4; ++mr) {
        #pragma unroll
        for (int nr = 0; nr < 2; ++nr) {
            #pragma unroll
            for (int r = 0; r < 4; ++r) {
                const int row = m0 + wm * 64 + mr * 16 + (lane >> 4) * 4 + r;
                const int col = n0 + wn * 32 + nr * 16 + (lane & 15);
                if (row < M && col < N) {
                    const float val = acc[mr][nr][r] + bias[col];
                    const int t = row >> 6, bb = row & 63;
                    C[(size_t)bb * (TT * VOC) + (size_t)t * VOC + col] = val;
                }
            }
        }
    }
}

__global__ __launch_bounds__(256) void k_mean(const float* __restrict__ f,
                                              float* __restrict__ mean_f)
{
    const int b = blockIdx.x;
    for (int e = threadIdx.x; e < ENC; e += 256) {
        float s = 0.f;
        for (int n = 0; n < NN; ++n) s += f[(size_t)(b * NN + n) * ENC + e];
        mean_f[(size_t)b * ENC + e] = s * (1.f / 49.f);
    }
}

__global__ __launch_bounds__(256) void k_init_partial(
    const float* __restrict__ mean_f,
    const float* __restrict__ iH_w, const float* __restrict__ iC_w,
    float* __restrict__ pbuf)
{
    const int tid = threadIdx.x;
    const int tx = tid & 15, ty = tid >> 4;
    const int n0 = blockIdx.x * 64;
    const int ks = blockIdx.y;
    __shared__ float As[16][64];
    __shared__ float Bs[16][64];
    float acc[4][4] = {};
    const int lrow = tid >> 2;
    const int lk = (tid & 3) * 4;
    for (int c = 0; c < 8; ++c) {
        const int kk = ks * 128 + c * 16 + lk;
        float4 av = *(const float4*)(mean_f + (size_t)lrow * 2048 + kk);
        const int col = n0 + lrow;
        const float* wp = (col < 512) ? (iH_w + (size_t)col * 2048)
                                      : (iC_w + (size_t)(col - 512) * 2048);
        float4 bv = *(const float4*)(wp + kk);
        As[lk + 0][lrow] = av.x; As[lk + 1][lrow] = av.y;
        As[lk + 2][lrow] = av.z; As[lk + 3][lrow] = av.w;
        Bs[lk + 0][lrow] = bv.x; Bs[lk + 1][lrow] = bv.y;
        Bs[lk + 2][lrow] = bv.z; Bs[lk + 3][lrow] = bv.w;
        __syncthreads();
        #pragma unroll
        for (int k = 0; k < 16; ++k) {
            float4 a = *(const float4*)&As[k][ty * 4];
            float4 b = *(const float4*)&Bs[k][tx * 4];
            acc[0][0] += a.x * b.x; acc[0][1] += a.x * b.y; acc[0][2] += a.x * b.z; acc[0][3] += a.x * b.w;
            acc[1][0] += a.y * b.x; acc[1][1] += a.y * b.y; acc[1][2] += a.y * b.z; acc[1][3] += a.y * b.w;
            acc[2][0] += a.z * b.x; acc[2][1] += a.z * b.y; acc[2][2] += a.z * b.z; acc[2][3] += a.z * b.w;
            acc[3][0] += a.w * b.x; acc[3][1] += a.w * b.y; acc[3][2] += a.w * b.z; acc[3][3] += a.w * b.w;
        }
        __syncthreads();
    }
    #pragma unroll
    for (int i = 0; i < 4; ++i) {
        const int r = ty * 4 + i;
        #pragma unroll
        for (int j = 0; j < 4; ++j)
            pbuf[(size_t)(ks * 64 + r) * 1024 + n0 + tx * 4 + j] = acc[i][j];
    }
}

__global__ __launch_bounds__(256) void k_init_reduce(
    const float* __restrict__ pbuf,
    const float* __restrict__ iH_b, const float* __restrict__ iC_b,
    float* __restrict__ h_cur, float* __restrict__ c_cur)
{
    const int idx = blockIdx.x * 256 + threadIdx.x;
    const int r = idx >> 10, c = idx & 1023;
    float s = 0.f;
    #pragma unroll
    for (int ks = 0; ks < 16; ++ks) s += pbuf[(size_t)(ks * 64 + r) * 1024 + c];
    if (c < 512) h_cur[r * 512 + c] = s + iH_b[c];
    else         c_cur[r * 512 + (c - 512)] = s + iC_b[c - 512];
}

__global__ void k_bias2(const float* __restrict__ a, const float* __restrict__ b,
                        float* __restrict__ o)
{
    const int j = blockIdx.x * 256 + threadIdx.x;
    if (j < 2048) o[j] = a[j] + b[j];
}

// flat f32 -> bf16 hi/lo split (n multiple of 4)
__global__ __launch_bounds__(256) void k_split(const float* __restrict__ src,
                                               u16* __restrict__ hi, u16* __restrict__ lo,
                                               int n)
{
    const int i = (blockIdx.x * 256 + threadIdx.x) * 4;
    if (i >= n) return;
    f32x4 v = *(const f32x4*)(src + i);
    s16x4 h4, l4;
    #pragma unroll
    for (int j = 0; j < 4; ++j) { short h, l; split_bf16(v[j], h, l); h4[j] = h; l4[j] = l; }
    *(s16x4*)(hi + i) = h4;
    *(s16x4*)(lo + i) = l4;
}

// strided split of ih_w[:, 300:2348] rows -> [2048][2048] hi/lo
__global__ __launch_bounds__(256) void k_splitW(const float* __restrict__ ih_w,
                                                u16* __restrict__ hi, u16* __restrict__ lo)
{
    const int r = blockIdx.x;
    const float* src = ih_w + (size_t)r * 2348 + 300;
    u16* hp = hi + (size_t)r * 2048;
    u16* lp = lo + (size_t)r * 2048;
    const int c = threadIdx.x * 8;
    #pragma unroll
    for (int g = 0; g < 2; ++g) {
        f32x4 v = *(const f32x4*)(src + c + g * 4);
        s16x4 h4, l4;
        #pragma unroll
        for (int j = 0; j < 4; ++j) { short h, l; split_bf16(v[j], h, l); h4[j] = h; l4[j] = l; }
        *(s16x4*)(hp + c + g * 4) = h4;
        *(s16x4*)(lp + c + g * 4) = l4;
    }
}

// ---------------------------------------------------------------------------
// wah/ghh split-K GEMV: grid (40, 8), 256 thr, K-slice 64, 1024 FMA/thread.
// Conflict-free LDS: cols/rows mapped tx + j*16 (bank stride 4).
// ---------------------------------------------------------------------------
__global__ __launch_bounds__(256) void k_hw8(
    const float* __restrict__ h,
    const float* __restrict__ W_w, const float* __restrict__ W_b,
    const float* __restrict__ hh_w,
    float* __restrict__ wahp, float* __restrict__ ghhp)
{
    const int tid = threadIdx.x;
    const int tx = tid & 15, ty = tid >> 4;
    const int n0 = blockIdx.x * 64;
    const int ks = blockIdx.y;   // 0..7
    const float* Bp; const float* biasp; float* Cp; int c0, ldc;
    if (n0 < 512) { Bp = W_w + (size_t)n0 * 512; biasp = (ks == 0) ? W_b : nullptr; Cp = wahp + (size_t)ks * 32768; c0 = n0; ldc = 512; }
    else { Bp = hh_w + (size_t)(n0 - 512) * 512; biasp = nullptr; Cp = ghhp + (size_t)ks * 131072; c0 = n0 - 512; ldc = 2048; }

    __shared__ float As[64][68];
    __shared__ float Bs[64][68];
    float acc[4][4] = {};
    const int rt = tid >> 2;
    const int cs = (tid & 3) * 16;
    const int kbase = ks * 64;

    #pragma unroll
    for (int i = 0; i < 4; ++i) {
        const int c = cs + i * 4;
        *(f32x4*)&As[rt][c] = *(const f32x4*)(h + (size_t)rt * 512 + kbase + c);
        *(f32x4*)&Bs[rt][c] = *(const f32x4*)(Bp + (size_t)rt * 512 + kbase + c);
    }
    __syncthreads();
    #pragma unroll 4
    for (int k4 = 0; k4 < 16; ++k4) {
        f32x4 a0 = *(const f32x4*)&As[ty + 0][k4 * 4];
        f32x4 a1 = *(const f32x4*)&As[ty + 16][k4 * 4];
        f32x4 a2 = *(const f32x4*)&As[ty + 32][k4 * 4];
        f32x4 a3 = *(const f32x4*)&As[ty + 48][k4 * 4];
        f32x4 b0 = *(const f32x4*)&Bs[tx + 0][k4 * 4];
        f32x4 b1 = *(const f32x4*)&Bs[tx + 16][k4 * 4];
        f32x4 b2 = *(const f32x4*)&Bs[tx + 32][k4 * 4];
        f32x4 b3 = *(const f32x4*)&Bs[tx + 48][k4 * 4];
        #pragma unroll
        for (int e = 0; e < 4; ++e) {
            acc[0][0] += a0[e] * b0[e]; acc[0][1] += a0[e] * b1[e];
            acc[0][2] += a0[e] * b2[e]; acc[0][3] += a0[e] * b3[e];
            acc[1][0] += a1[e] * b0[e]; acc[1][1] += a1[e] * b1[e];
            acc[1][2] += a1[e] * b2[e]; acc[1][3] += a1[e] * b3[e];
            acc[2][0] += a2[e] * b0[e]; acc[2][1] += a2[e] * b1[e];
            acc[2][2] += a2[e] * b2[e]; acc[2][3] += a2[e] * b3[e];
            acc[3][0] += a3[e] * b0[e]; acc[3][1] += a3[e] * b1[e];
            acc[3][2] += a3[e] * b2[e]; acc[3][3] += a3[e] * b3[e];
        }
    }
    #pragma unroll
    for (int i = 0; i < 4; ++i) {
        const int r = ty + i * 16;     // batch b
        #pragma unroll
        for (int j = 0; j < 4; ++j) {
            const int cc = c0 + tx + j * 16;
            Cp[(size_t)r * ldc + cc] = acc[i][j] + (biasp ? biasp[cc] : 0.f);
        }
    }
}

// ---------------------------------------------------------------------------
// Fused per-step kernel v5: grid (64 b, 4 d-quadrants), 512 threads.
// 8-way split-K partial sums; coalesced scores; register fW contraction.
// ---------------------------------------------------------------------------
__global__ __launch_bounds__(512) void k_fused5(
    const u16* __restrict__ uhs16,
    const float* __restrict__ A_w, const float* __restrict__ A_b,
    const float* __restrict__ wahp,  // [8][64][512]
    const float* __restrict__ ghhp,  // [8][64][2048]
    const float* __restrict__ pre_x, // [1920][2048] incl. ih_b+hh_b
    const u16* __restrict__ fW16,    // [64*49][2048] bf16
    float* __restrict__ h_cur, float* __restrict__ c_cur,
    u16* __restrict__ Hall_h, u16* __restrict__ Hall_l,
    float* __restrict__ alphas, int s)
{
    const int bb = blockIdx.x;
    const int qq = blockIdx.y;
    const int tid = threadIdx.x;
    const int lane = tid & 63, w = tid >> 6;
    __shared__ float wah_l[512];
    __shared__ float red[64];
    __shared__ float al[64];
    __shared__ float ghl[512];
    __shared__ float gl[512];

    // ---- independent loads up front ----
    const int gate = tid >> 7, dloc = tid & 127;
    const int jcol = gate * 512 + qq * 128 + dloc;
    float ghv = pre_x[(size_t)(s * 64 + bb) * 2048 + jcol];
    #pragma unroll
    for (int i = 0; i < 8; ++i)
        ghv += ghhp[(size_t)i * 131072 + (size_t)bb * 2048 + jcol];
    float wv = 0.f;
    #pragma unroll
    for (int i = 0; i < 8; ++i)
        wv += wahp[(size_t)i * 32768 + bb * 512 + tid];
    const float cload = c_cur[bb * 512 + qq * 128 + (tid & 127)];

    const int a0 = lane * 8;
    float aw8[8];
    #pragma unroll
    for (int k = 0; k < 8; ++k) aw8[k] = A_w[a0 + k];

    // fW fragment prefetch: thread = (ngf fast, colgroup)
    const int ngf = tid & 7, r = tid >> 3;
    const int gf = r >> 4, oc = r & 15;
    const int jb = gf * 512 + qq * 128 + oc * 8;
    const u16* fb = fW16 + (size_t)bb * NN * 2048 + jb;
    s16x8 pf[7];
    #pragma unroll
    for (int i = 0; i < 7; ++i) {
        const int n = ngf + 8 * i;
        if (n < NN) pf[i] = *(const s16x8*)(fb + (size_t)n * 2048);
        else        pf[i] = (s16x8){0, 0, 0, 0, 0, 0, 0, 0};
    }

    ghl[tid] = ghv;
    wah_l[tid] = wv;
    __syncthreads();

    float wh8[8];
    #pragma unroll
    for (int k = 0; k < 8; ++k) wh8[k] = wah_l[a0 + k];

    // ---- scores: 7 rows per wave, coalesced 16B/lane loads ----
    const u16* ub = uhs16 + (size_t)(bb * NN) * 512 + a0;
    #pragma unroll
    for (int i = 0; i < 7; ++i) {
        const int n = w + 8 * i;
        const int nc = (n < NN) ? n : 0;
        const s16x8 uv = *(const s16x8*)(ub + (size_t)nc * 512);
        float acc = 0.f;
        #pragma unroll
        for (int k = 0; k < 8; ++k)
            acc += aw8[k] * fast_tanh(bf2f((u16)uv[k]) + wh8[k]);
        #pragma unroll
        for (int m = 32; m; m >>= 1) acc += __shfl_xor(acc, m, 64);
        if (lane == 0 && n < NN) red[n] = acc + A_b[0];
    }
    __syncthreads();

    // ---- softmax (wave 0) ----
    if (tid < 64) {
        const float sc = (tid < NN) ? red[tid] : -1e30f;
        float mx = sc;
        #pragma unroll
        for (int m = 32; m; m >>= 1) mx = fmaxf(mx, __shfl_xor(mx, m, 64));
        float e = (tid < NN) ? __expf(sc - mx) : 0.f;
        float sum = e;
        #pragma unroll
        for (int m = 32; m; m >>= 1) sum += __shfl_xor(sum, m, 64);
        const float av = e / sum;
        al[tid] = av;
        if (qq == 0 && tid < NN)
            alphas[(size_t)bb * (TT * NN) + (size_t)s * NN + tid] = av;
    }
    __syncthreads();

    // ---- contraction from prefetched registers; 8-lane shuffle reduce ----
    float a8[8] = {0.f, 0.f, 0.f, 0.f, 0.f, 0.f, 0.f, 0.f};
    #pragma unroll
    for (int i = 0; i < 7; ++i) {
        const int n = ngf + 8 * i;          // al[n>=49] == 0
        const float av = al[n];
        #pragma unroll
        for (int k = 0; k < 8; ++k)
            a8[k] += av * bf2f((u16)pf[i][k]);
    }
    #pragma unroll
    for (int m = 1; m < 8; m <<= 1)
        #pragma unroll
        for (int k = 0; k < 8; ++k)
            a8[k] += __shfl_xor(a8[k], m, 64);
    if (ngf == 0) {
        const int base = gf * 128 + oc * 8;
        #pragma unroll
        for (int k = 0; k < 8; ++k)
            gl[base + k] = a8[k] + ghl[base + k];
    }
    __syncthreads();

    // ---- pointwise LSTM ----
    if (tid < 128) {
        const int dd = qq * 128 + tid;
        const float ig = sigmoidf(gl[tid]);
        const float fg = sigmoidf(gl[128 + tid]);
        const float gg = fast_tanh(gl[256 + tid]);
        const float og = sigmoidf(gl[384 + tid]);
        const float cv = fg * cload + ig * gg;
        const float hv = og * fast_tanh(cv);
        c_cur[bb * 512 + dd] = cv;
        h_cur[bb * 512 + dd] = hv;
        short hh, hl;
        split_bf16(hv, hh, hl);
        Hall_h[(size_t)(s * 64 + bb) * 512 + dd] = (u16)hh;
        Hall_l[(size_t)(s * 64 + bb) * 512 + dd] = (u16)hl;
    }
}

// ---------------------------------------------------------------------------
extern "C" void kernel_launch(void* const* d_in, const int* in_sizes, int n_in,
                              void* d_out, int out_size, void* d_ws, size_t ws_size,
                              hipStream_t stream)
{
    const float* features = (const float*)d_in[0];
    const int*   captions = (const int*)d_in[1];
    const float* emb      = (const float*)d_in[2];
    const float* U_w      = (const float*)d_in[3];
    const float* U_b      = (const float*)d_in[4];
    const float* W_w      = (const float*)d_in[5];
    const float* W_b      = (const float*)d_in[6];
    const float* A_w      = (const float*)d_in[7];
    const float* A_b      = (const float*)d_in[8];
    const float* iH_w     = (const float*)d_in[9];
    const float* iH_b     = (const float*)d_in[10];
    const float* iC_w     = (const float*)d_in[11];
    const float* iC_b     = (const float*)d_in[12];
    const float* ih_w     = (const float*)d_in[13];
    const float* ih_b     = (const float*)d_in[14];
    const float* hh_w     = (const float*)d_in[15];
    const float* hh_b     = (const float*)d_in[16];
    const float* fcn_w    = (const float*)d_in[17];
    const float* fcn_b    = (const float*)d_in[18];

    float* out    = (float*)d_out;
    float* alphas = out + (size_t)B * TT * VOC;

    float* ws     = (float*)d_ws;
    // layout (float offsets); total 16,730,112 floats = 66.9 MB
    u16*  fW16    = (u16*)ws;                      // 3,211,264 f
    u16*  uhs16   = (u16*)(ws + 3211264);          //   802,816 f
    float* pre_x  = ws + 4014080;                  // 3,932,160 f
    u16*  Hall_h  = (u16*)(ws + 7946240);          //   491,520 f
    u16*  Hall_l  = (u16*)(ws + 8437760);          //   491,520 f
    float* h_cur  = ws + 8929280;                  //    32,768
    float* c_cur  = ws + 8962048;                  //    32,768
    float* wahp   = ws + 8994816;                  //   262,144 (8*64*512)
    float* ghhp   = ws + 9256960;                  // 1,048,576 (8*64*2048)
    float* bias2  = ws + 10305536;                 //     2,048
    u16*  fhi     = (u16*)(ws + 10307584);         // 3,211,264 f
    u16*  flo     = (u16*)(ws + 13518848);         // 3,211,264 f
    // aliases over dead producers:
    float* pbuf   = ws;                            // init partials (in fW16 region)
    float* mean_f = ws + 1048576;                  // after pbuf, still in fW16 region
    u16*  ihw_h   = (u16*)pre_x;                   // 2,097,152 f (pre-split ih_w hi)
    u16*  ihw_l   = (u16*)(ws + 6111232);          // 2,097,152 f (ends inside Hall_h)
    u16*  fcnw_h  = fhi;                           // fcn_w split (after mfma_cat2)
    u16*  fcnw_l  = flo;

    // init hidden state
    k_mean<<<64, 256, 0, stream>>>(features, mean_f);
    k_init_partial<<<dim3(16, 16), 256, 0, stream>>>(mean_f, iH_w, iC_w, pbuf);
    k_init_reduce<<<256, 256, 0, stream>>>(pbuf, iH_b, iC_b, h_cur, c_cur);

    // hoisted precomputes
    k_bias2<<<8, 256, 0, stream>>>(ih_b, hh_b, bias2);
    k_split<<<6272, 256, 0, stream>>>(features, fhi, flo, B * NN * ENC);
    k_splitW<<<2048, 256, 0, stream>>>(ih_w, ihw_h, ihw_l);
    // combined u_hs+fW GEMM: [3136 x 2560] over K=2048
    mfma_cat2<<<dim3(20, 25), 512, 0, stream>>>(fhi, flo, U_w, U_b, ihw_h, ihw_l,
                                                uhs16, fW16, B * NN);
    // fcn_w split (fhi/flo dead after mfma_cat2)
    k_split<<<5000, 256, 0, stream>>>(fcn_w, fcnw_h, fcnw_l, VOC * DEC);
    // pre_x with fused embedding gather (overwrites dead ihw buffers)
    mfma_prex<<<dim3(16, 15), 512, 0, stream>>>(captions, emb, ih_w, bias2, pre_x);

    // recurrence
    k_hw8<<<dim3(40, 8), 256, 0, stream>>>(h_cur, W_w, W_b, hh_w, wahp, ghhp);
    for (int s = 0; s < TT; ++s) {
        k_fused5<<<dim3(64, 4), 512, 0, stream>>>(uhs16, A_w, A_b, wahp, ghhp, pre_x, fW16,
                                                  h_cur, c_cur, Hall_h, Hall_l, alphas, s);
        if (s < TT - 1)
            k_hw8<<<dim3(40, 8), 256, 0, stream>>>(h_cur, W_w, W_b, hh_w, wahp, ghhp);
    }

    // output projection on pre-split bf16
    mfma_pre<<<dim3(79, 15), 512, 0, stream>>>(Hall_h, Hall_l, fcnw_h, fcnw_l, fcn_b,
                                               out, TT * B, VOC);
}

// Round 10
// 896.350 us; speedup vs baseline: 1.0360x; 1.0360x over previous
//
#include <hip/hip_runtime.h>
#include <math.h>

// Problem constants
#define B 64
#define NN 49
#define ENC 2048
#define DEC 512
#define ATT 512
#define EMB 300
#define VOC 10000
#define TT 30

typedef __attribute__((ext_vector_type(4))) float f32x4;
typedef __attribute__((ext_vector_type(4))) short s16x4;
typedef __attribute__((ext_vector_type(8))) short s16x8;
typedef unsigned short u16;

__device__ __forceinline__ float fast_tanh(float x) {
    float e = __expf(2.f * x);
    return 1.f - 2.f / (e + 1.f);
}
__device__ __forceinline__ float sigmoidf(float x) {
    return 1.f / (1.f + __expf(-x));
}
__device__ __forceinline__ u16 f2bf(float x) {
    unsigned u = __float_as_uint(x);
    unsigned r = u + 0x7FFFu + ((u >> 16) & 1u);
    return (u16)(r >> 16);
}
__device__ __forceinline__ float bf2f(u16 u) {
    return __uint_as_float((unsigned)u << 16);
}
__device__ __forceinline__ void split_bf16(float x, short& hi, short& lo) {
    u16 h = f2bf(x);
    float hf = __uint_as_float((unsigned)h << 16);
    hi = (short)h;
    lo = (short)f2bf(x - hf);
}
__device__ __forceinline__ s16x8 ld8(const short* p) {
    s16x4 a = *(const s16x4*)p;
    s16x4 b = *(const s16x4*)(p + 4);
    return __builtin_shufflevector(a, b, 0, 1, 2, 3, 4, 5, 6, 7);
}
// bijective XCD swizzle (m204): contiguous chunk per XCD
__device__ __forceinline__ int xcd_swz(int bid, int nwg) {
    const int q = nwg >> 3, r = nwg & 7;
    const int xcd = bid & 7, idx = bid >> 3;
    return ((xcd < r) ? xcd * (q + 1) : r * (q + 1) + (xcd - r) * q) + idx;
}

// ---------------------------------------------------------------------------
// mfma_cat2: A = pre-split features (hi/lo), B = [U_w (on-the-fly) ;
// pre-split ih_w slice]. K=2048, N=2560. col<512 -> uhs16 (+U_b), else fW16.
// XCD-swizzled block mapping.
// ---------------------------------------------------------------------------
__global__ __launch_bounds__(512) void mfma_cat2(
    const u16* __restrict__ fhi, const u16* __restrict__ flo,
    const float* __restrict__ U_w, const float* __restrict__ U_b,
    const u16* __restrict__ ihw_h, const u16* __restrict__ ihw_l,
    u16* __restrict__ uhs16, u16* __restrict__ fW16, int M)
{
    __shared__ short Ah[128][40];
    __shared__ short Al[128][40];
    __shared__ short Bh[128][40];
    __shared__ short Bl[128][40];

    const int tid = threadIdx.x;
    const int nwg = gridDim.x * gridDim.y;                    // 500
    const int swz = xcd_swz(blockIdx.y * gridDim.x + blockIdx.x, nwg);
    const int m0 = (swz / gridDim.x) * 128;
    const int n0 = (swz % gridDim.x) * 128;
    const int wid = tid >> 6, lane = tid & 63;
    const int wm = wid >> 2, wn = wid & 3;
    const int lrow = lane & 15;
    const int lko = (lane >> 4) * 8;
    const int srow = tid >> 2;
    const int sk = (tid & 3) * 8;

    const int gc = n0 + srow;
    const int gr = m0 + srow;
    const u16* ahp = fhi + (size_t)gr * 2048;
    const u16* alp = flo + (size_t)gr * 2048;

    f32x4 acc[4][2];
    #pragma unroll
    for (int i = 0; i < 4; ++i)
        #pragma unroll
        for (int j = 0; j < 2; ++j)
            acc[i][j] = (f32x4){0.f, 0.f, 0.f, 0.f};

    for (int kt = 0; kt < 64; ++kt) {
        const int kb0 = kt * 32 + sk;
        {
            s16x8 vh = {0,0,0,0,0,0,0,0}, vl = {0,0,0,0,0,0,0,0};
            if (gr < M) {
                vh = *(const s16x8*)(ahp + kb0);
                vl = *(const s16x8*)(alp + kb0);
            }
            *(s16x8*)&Ah[srow][sk] = vh;
            *(s16x8*)&Al[srow][sk] = vl;
        }
        if (n0 < 512) {   // U_w columns: split on the fly (uniform per block)
            const float* bp = U_w + (size_t)gc * 2048;
            float4 x0 = *(const float4*)(bp + kb0);
            float4 x1 = *(const float4*)(bp + kb0 + 4);
            float v[8] = {x0.x, x0.y, x0.z, x0.w, x1.x, x1.y, x1.z, x1.w};
            s16x4 h0, h1, l0, l1;
            #pragma unroll
            for (int j = 0; j < 4; ++j) { short h, l; split_bf16(v[j], h, l); h0[j] = h; l0[j] = l; }
            #pragma unroll
            for (int j = 0; j < 4; ++j) { short h, l; split_bf16(v[4 + j], h, l); h1[j] = h; l1[j] = l; }
            *(s16x4*)&Bh[srow][sk] = h0; *(s16x4*)&Bh[srow][sk + 4] = h1;
            *(s16x4*)&Bl[srow][sk] = l0; *(s16x4*)&Bl[srow][sk + 4] = l1;
        } else {          // pre-split ih_w columns
            *(s16x8*)&Bh[srow][sk] = *(const s16x8*)(ihw_h + (size_t)(gc - 512) * 2048 + kb0);
            *(s16x8*)&Bl[srow][sk] = *(const s16x8*)(ihw_l + (size_t)(gc - 512) * 2048 + kb0);
        }
        __syncthreads();

        s16x8 bh[2], bl[2];
        #pragma unroll
        for (int nr = 0; nr < 2; ++nr) {
            const int col = wn * 32 + nr * 16 + lrow;
            bh[nr] = ld8(&Bh[col][lko]);
            bl[nr] = ld8(&Bl[col][lko]);
        }
        #pragma unroll
        for (int mr = 0; mr < 4; ++mr) {
            const int row = wm * 64 + mr * 16 + lrow;
            s16x8 ah = ld8(&Ah[row][lko]);
            s16x8 al = ld8(&Al[row][lko]);
            #pragma unroll
            for (int nr = 0; nr < 2; ++nr) {
                acc[mr][nr] = __builtin_amdgcn_mfma_f32_16x16x32_bf16(ah, bh[nr], acc[mr][nr], 0, 0, 0);
                acc[mr][nr] = __builtin_amdgcn_mfma_f32_16x16x32_bf16(ah, bl[nr], acc[mr][nr], 0, 0, 0);
                acc[mr][nr] = __builtin_amdgcn_mfma_f32_16x16x32_bf16(al, bh[nr], acc[mr][nr], 0, 0, 0);
            }
        }
        __syncthreads();
    }

    #pragma unroll
    for (int mr = 0; mr < 4; ++mr) {
        #pragma unroll
        for (int nr = 0; nr < 2; ++nr) {
            #pragma unroll
            for (int r = 0; r < 4; ++r) {
                const int row = m0 + wm * 64 + mr * 16 + (lane >> 4) * 4 + r;
                const int col = n0 + wn * 32 + nr * 16 + (lane & 15);
                if (row < M) {
                    if (col < 512)
                        uhs16[(size_t)row * 512 + col] = f2bf(acc[mr][nr][r] + U_b[col]);
                    else
                        fW16[(size_t)row * 2048 + (col - 512)] = f2bf(acc[mr][nr][r]);
                }
            }
        }
    }
}

// ---------------------------------------------------------------------------
// mfma_prex: pre_x = gather(emb, captions) @ ih_w[:, :300]^T + bias2.
// ---------------------------------------------------------------------------
__global__ __launch_bounds__(512) void mfma_prex(
    const int* __restrict__ cap,
    const float* __restrict__ emb,
    const float* __restrict__ ih_w,
    const float* __restrict__ bias2,
    float* __restrict__ pre_x)
{
    __shared__ short Ah[128][40];
    __shared__ short Al[128][40];
    __shared__ short Bh[128][40];
    __shared__ short Bl[128][40];

    const int tid = threadIdx.x;
    const int m0 = blockIdx.y * 128, n0 = blockIdx.x * 128;
    const int wid = tid >> 6, lane = tid & 63;
    const int wm = wid >> 2, wn = wid & 3;
    const int lrow = lane & 15;
    const int lko = (lane >> 4) * 8;
    const int srow = tid >> 2;
    const int sk = (tid & 3) * 8;

    const int gr = m0 + srow;
    const int tt = gr >> 6, bbs = gr & 63;
    const float* ap = emb + (size_t)cap[bbs * 31 + tt] * 300;
    const int gc = n0 + srow;
    const float* bp = ih_w + (size_t)gc * 2348;

    f32x4 acc[4][2];
    #pragma unroll
    for (int i = 0; i < 4; ++i)
        #pragma unroll
        for (int j = 0; j < 2; ++j)
            acc[i][j] = (f32x4){0.f, 0.f, 0.f, 0.f};

    for (int kt = 0; kt < 10; ++kt) {
        const int kb0 = kt * 32 + sk;
        {
            float v[8];
            if (kb0 + 7 < 300) {
                float4 x0 = *(const float4*)(ap + kb0);
                float4 x1 = *(const float4*)(ap + kb0 + 4);
                v[0] = x0.x; v[1] = x0.y; v[2] = x0.z; v[3] = x0.w;
                v[4] = x1.x; v[5] = x1.y; v[6] = x1.z; v[7] = x1.w;
            } else {
                #pragma unroll
                for (int j = 0; j < 8; ++j)
                    v[j] = (kb0 + j < 300) ? ap[kb0 + j] : 0.f;
            }
            s16x4 h0, h1, l0, l1;
            #pragma unroll
            for (int j = 0; j < 4; ++j) { short h, l; split_bf16(v[j], h, l); h0[j] = h; l0[j] = l; }
            #pragma unroll
            for (int j = 0; j < 4; ++j) { short h, l; split_bf16(v[4 + j], h, l); h1[j] = h; l1[j] = l; }
            *(s16x4*)&Ah[srow][sk] = h0; *(s16x4*)&Ah[srow][sk + 4] = h1;
            *(s16x4*)&Al[srow][sk] = l0; *(s16x4*)&Al[srow][sk + 4] = l1;
        }
        {
            float v[8];
            if (kb0 + 7 < 300) {
                float4 x0 = *(const float4*)(bp + kb0);
                float4 x1 = *(const float4*)(bp + kb0 + 4);
                v[0] = x0.x; v[1] = x0.y; v[2] = x0.z; v[3] = x0.w;
                v[4] = x1.x; v[5] = x1.y; v[6] = x1.z; v[7] = x1.w;
            } else {
                #pragma unroll
                for (int j = 0; j < 8; ++j)
                    v[j] = (kb0 + j < 300) ? bp[kb0 + j] : 0.f;
            }
            s16x4 h0, h1, l0, l1;
            #pragma unroll
            for (int j = 0; j < 4; ++j) { short h, l; split_bf16(v[j], h, l); h0[j] = h; l0[j] = l; }
            #pragma unroll
            for (int j = 0; j < 4; ++j) { short h, l; split_bf16(v[4 + j], h, l); h1[j] = h; l1[j] = l; }
            *(s16x4*)&Bh[srow][sk] = h0; *(s16x4*)&Bh[srow][sk + 4] = h1;
            *(s16x4*)&Bl[srow][sk] = l0; *(s16x4*)&Bl[srow][sk + 4] = l1;
        }
        __syncthreads();

        s16x8 bh[2], bl[2];
        #pragma unroll
        for (int nr = 0; nr < 2; ++nr) {
            const int col = wn * 32 + nr * 16 + lrow;
            bh[nr] = ld8(&Bh[col][lko]);
            bl[nr] = ld8(&Bl[col][lko]);
        }
        #pragma unroll
        for (int mr = 0; mr < 4; ++mr) {
            const int row = wm * 64 + mr * 16 + lrow;
            s16x8 ah = ld8(&Ah[row][lko]);
            s16x8 al = ld8(&Al[row][lko]);
            #pragma unroll
            for (int nr = 0; nr < 2; ++nr) {
                acc[mr][nr] = __builtin_amdgcn_mfma_f32_16x16x32_bf16(ah, bh[nr], acc[mr][nr], 0, 0, 0);
                acc[mr][nr] = __builtin_amdgcn_mfma_f32_16x16x32_bf16(ah, bl[nr], acc[mr][nr], 0, 0, 0);
                acc[mr][nr] = __builtin_amdgcn_mfma_f32_16x16x32_bf16(al, bh[nr], acc[mr][nr], 0, 0, 0);
            }
        }
        __syncthreads();
    }

    #pragma unroll
    for (int mr = 0; mr < 4; ++mr) {
        #pragma unroll
        for (int nr = 0; nr < 2; ++nr) {
            #pragma unroll
            for (int r = 0; r < 4; ++r) {
                const int row = m0 + wm * 64 + mr * 16 + (lane >> 4) * 4 + r;
                const int col = n0 + wn * 32 + nr * 16 + (lane & 15);
                pre_x[(size_t)row * 2048 + col] = acc[mr][nr][r] + bias2[col];
            }
        }
    }
}

// ---------------------------------------------------------------------------
// mfma_pre2: 2-term output GEMM. A = Hall bf16 (hi only), B = fcn_w hi/lo.
// K=512, preds scatter + bias. XCD-swizzled blocks. LDS 3 tiles (30 KB).
// ---------------------------------------------------------------------------
__global__ __launch_bounds__(512) void mfma_pre2(
    const u16* __restrict__ Ahg,
    const u16* __restrict__ Bhg, const u16* __restrict__ Blg,
    const float* __restrict__ bias,
    float* __restrict__ C, int M, int N)
{
    __shared__ short Ah[128][40];
    __shared__ short Bh[128][40];
    __shared__ short Bl[128][40];

    const int tid = threadIdx.x;
    const int nwg = gridDim.x * gridDim.y;                    // 1185
    const int swz = xcd_swz(blockIdx.y * gridDim.x + blockIdx.x, nwg);
    const int m0 = (swz / gridDim.x) * 128;
    const int n0 = (swz % gridDim.x) * 128;
    const int wid = tid >> 6, lane = tid & 63;
    const int wm = wid >> 2, wn = wid & 3;
    const int lrow = lane & 15;
    const int lko = (lane >> 4) * 8;
    const int srow = tid >> 2;
    const int sk = (tid & 3) * 8;

    f32x4 acc[4][2];
    #pragma unroll
    for (int i = 0; i < 4; ++i)
        #pragma unroll
        for (int j = 0; j < 2; ++j)
            acc[i][j] = (f32x4){0.f, 0.f, 0.f, 0.f};

    for (int kt = 0; kt < 16; ++kt) {
        const int kb0 = kt * 32 + sk;
        {
            const int gr = m0 + srow;
            s16x8 vh = {0,0,0,0,0,0,0,0};
            if (gr < M) vh = *(const s16x8*)(Ahg + (size_t)gr * 512 + kb0);
            *(s16x8*)&Ah[srow][sk] = vh;
        }
        {
            const int gc = n0 + srow;
            s16x8 vh = {0,0,0,0,0,0,0,0}, vl = {0,0,0,0,0,0,0,0};
            if (gc < N) {
                vh = *(const s16x8*)(Bhg + (size_t)gc * 512 + kb0);
                vl = *(const s16x8*)(Blg + (size_t)gc * 512 + kb0);
            }
            *(s16x8*)&Bh[srow][sk] = vh;
            *(s16x8*)&Bl[srow][sk] = vl;
        }
        __syncthreads();

        s16x8 bh[2], bl[2];
        #pragma unroll
        for (int nr = 0; nr < 2; ++nr) {
            const int col = wn * 32 + nr * 16 + lrow;
            bh[nr] = ld8(&Bh[col][lko]);
            bl[nr] = ld8(&Bl[col][lko]);
        }
        #pragma unroll
        for (int mr = 0; mr < 4; ++mr) {
            const int row = wm * 64 + mr * 16 + lrow;
            s16x8 ah = ld8(&Ah[row][lko]);
            #pragma unroll
            for (int nr = 0; nr < 2; ++nr) {
                acc[mr][nr] = __builtin_amdgcn_mfma_f32_16x16x32_bf16(ah, bh[nr], acc[mr][nr], 0, 0, 0);
                acc[mr][nr] = __builtin_amdgcn_mfma_f32_16x16x32_bf16(ah, bl[nr], acc[mr][nr], 0, 0, 0);
            }
        }
        __syncthreads();
    }

    #pragma unroll
    for (int mr = 0; mr < 4; ++mr) {
        #pragma unroll
        for (int nr = 0; nr < 2; ++nr) {
            #pragma unroll
            for (int r = 0; r < 4; ++r) {
                const int row = m0 + wm * 64 + mr * 16 + (lane >> 4) * 4 + r;
                const int col = n0 + wn * 32 + nr * 16 + (lane & 15);
                if (row < M && col < N) {
                    const float val = acc[mr][nr][r] + bias[col];
                    const int t = row >> 6, bb = row & 63;
                    C[(size_t)bb * (TT * VOC) + (size_t)t * VOC + col] = val;
                }
            }
        }
    }
}

__global__ __launch_bounds__(256) void k_mean(const float* __restrict__ f,
                                              float* __restrict__ mean_f)
{
    const int b = blockIdx.x;
    for (int e = threadIdx.x; e < ENC; e += 256) {
        float s = 0.f;
        for (int n = 0; n < NN; ++n) s += f[(size_t)(b * NN + n) * ENC + e];
        mean_f[(size_t)b * ENC + e] = s * (1.f / 49.f);
    }
}

__global__ __launch_bounds__(256) void k_init_partial(
    const float* __restrict__ mean_f,
    const float* __restrict__ iH_w, const float* __restrict__ iC_w,
    float* __restrict__ pbuf)
{
    const int tid = threadIdx.x;
    const int tx = tid & 15, ty = tid >> 4;
    const int n0 = blockIdx.x * 64;
    const int ks = blockIdx.y;
    __shared__ float As[16][64];
    __shared__ float Bs[16][64];
    float acc[4][4] = {};
    const int lrow = tid >> 2;
    const int lk = (tid & 3) * 4;
    for (int c = 0; c < 8; ++c) {
        const int kk = ks * 128 + c * 16 + lk;
        float4 av = *(const float4*)(mean_f + (size_t)lrow * 2048 + kk);
        const int col = n0 + lrow;
        const float* wp = (col < 512) ? (iH_w + (size_t)col * 2048)
                                      : (iC_w + (size_t)(col - 512) * 2048);
        float4 bv = *(const float4*)(wp + kk);
        As[lk + 0][lrow] = av.x; As[lk + 1][lrow] = av.y;
        As[lk + 2][lrow] = av.z; As[lk + 3][lrow] = av.w;
        Bs[lk + 0][lrow] = bv.x; Bs[lk + 1][lrow] = bv.y;
        Bs[lk + 2][lrow] = bv.z; Bs[lk + 3][lrow] = bv.w;
        __syncthreads();
        #pragma unroll
        for (int k = 0; k < 16; ++k) {
            float4 a = *(const float4*)&As[k][ty * 4];
            float4 b = *(const float4*)&Bs[k][tx * 4];
            acc[0][0] += a.x * b.x; acc[0][1] += a.x * b.y; acc[0][2] += a.x * b.z; acc[0][3] += a.x * b.w;
            acc[1][0] += a.y * b.x; acc[1][1] += a.y * b.y; acc[1][2] += a.y * b.z; acc[1][3] += a.y * b.w;
            acc[2][0] += a.z * b.x; acc[2][1] += a.z * b.y; acc[2][2] += a.z * b.z; acc[2][3] += a.z * b.w;
            acc[3][0] += a.w * b.x; acc[3][1] += a.w * b.y; acc[3][2] += a.w * b.z; acc[3][3] += a.w * b.w;
        }
        __syncthreads();
    }
    #pragma unroll
    for (int i = 0; i < 4; ++i) {
        const int r = ty * 4 + i;
        #pragma unroll
        for (int j = 0; j < 4; ++j)
            pbuf[(size_t)(ks * 64 + r) * 1024 + n0 + tx * 4 + j] = acc[i][j];
    }
}

__global__ __launch_bounds__(256) void k_init_reduce(
    const float* __restrict__ pbuf,
    const float* __restrict__ iH_b, const float* __restrict__ iC_b,
    float* __restrict__ h_cur, float* __restrict__ c_cur)
{
    const int idx = blockIdx.x * 256 + threadIdx.x;
    const int r = idx >> 10, c = idx & 1023;
    float s = 0.f;
    #pragma unroll
    for (int ks = 0; ks < 16; ++ks) s += pbuf[(size_t)(ks * 64 + r) * 1024 + c];
    if (c < 512) h_cur[r * 512 + c] = s + iH_b[c];
    else         c_cur[r * 512 + (c - 512)] = s + iC_b[c - 512];
}

__global__ void k_bias2(const float* __restrict__ a, const float* __restrict__ b,
                        float* __restrict__ o)
{
    const int j = blockIdx.x * 256 + threadIdx.x;
    if (j < 2048) o[j] = a[j] + b[j];
}

// flat f32 -> bf16 hi/lo split (n multiple of 4)
__global__ __launch_bounds__(256) void k_split(const float* __restrict__ src,
                                               u16* __restrict__ hi, u16* __restrict__ lo,
                                               int n)
{
    const int i = (blockIdx.x * 256 + threadIdx.x) * 4;
    if (i >= n) return;
    f32x4 v = *(const f32x4*)(src + i);
    s16x4 h4, l4;
    #pragma unroll
    for (int j = 0; j < 4; ++j) { short h, l; split_bf16(v[j], h, l); h4[j] = h; l4[j] = l; }
    *(s16x4*)(hi + i) = h4;
    *(s16x4*)(lo + i) = l4;
}

// strided split of ih_w[:, 300:2348] rows -> [2048][2048] hi/lo
__global__ __launch_bounds__(256) void k_splitW(const float* __restrict__ ih_w,
                                                u16* __restrict__ hi, u16* __restrict__ lo)
{
    const int r = blockIdx.x;
    const float* src = ih_w + (size_t)r * 2348 + 300;
    u16* hp = hi + (size_t)r * 2048;
    u16* lp = lo + (size_t)r * 2048;
    const int c = threadIdx.x * 8;
    #pragma unroll
    for (int g = 0; g < 2; ++g) {
        f32x4 v = *(const f32x4*)(src + c + g * 4);
        s16x4 h4, l4;
        #pragma unroll
        for (int j = 0; j < 4; ++j) { short h, l; split_bf16(v[j], h, l); h4[j] = h; l4[j] = l; }
        *(s16x4*)(hp + c + g * 4) = h4;
        *(s16x4*)(lp + c + g * 4) = l4;
    }
}

// ---------------------------------------------------------------------------
// wah/ghh split-K GEMV: grid (40, 8), 256 thr, K-slice 64, 1024 FMA/thread.
// Conflict-free LDS: cols/rows mapped tx + j*16 (bank stride 4).
// ---------------------------------------------------------------------------
__global__ __launch_bounds__(256) void k_hw8(
    const float* __restrict__ h,
    const float* __restrict__ W_w, const float* __restrict__ W_b,
    const float* __restrict__ hh_w,
    float* __restrict__ wahp, float* __restrict__ ghhp)
{
    const int tid = threadIdx.x;
    const int tx = tid & 15, ty = tid >> 4;
    const int n0 = blockIdx.x * 64;
    const int ks = blockIdx.y;   // 0..7
    const float* Bp; const float* biasp; float* Cp; int c0, ldc;
    if (n0 < 512) { Bp = W_w + (size_t)n0 * 512; biasp = (ks == 0) ? W_b : nullptr; Cp = wahp + (size_t)ks * 32768; c0 = n0; ldc = 512; }
    else { Bp = hh_w + (size_t)(n0 - 512) * 512; biasp = nullptr; Cp = ghhp + (size_t)ks * 131072; c0 = n0 - 512; ldc = 2048; }

    __shared__ float As[64][68];
    __shared__ float Bs[64][68];
    float acc[4][4] = {};
    const int rt = tid >> 2;
    const int cs = (tid & 3) * 16;
    const int kbase = ks * 64;

    #pragma unroll
    for (int i = 0; i < 4; ++i) {
        const int c = cs + i * 4;
        *(f32x4*)&As[rt][c] = *(const f32x4*)(h + (size_t)rt * 512 + kbase + c);
        *(f32x4*)&Bs[rt][c] = *(const f32x4*)(Bp + (size_t)rt * 512 + kbase + c);
    }
    __syncthreads();
    #pragma unroll 4
    for (int k4 = 0; k4 < 16; ++k4) {
        f32x4 a0 = *(const f32x4*)&As[ty + 0][k4 * 4];
        f32x4 a1 = *(const f32x4*)&As[ty + 16][k4 * 4];
        f32x4 a2 = *(const f32x4*)&As[ty + 32][k4 * 4];
        f32x4 a3 = *(const f32x4*)&As[ty + 48][k4 * 4];
        f32x4 b0 = *(const f32x4*)&Bs[tx + 0][k4 * 4];
        f32x4 b1 = *(const f32x4*)&Bs[tx + 16][k4 * 4];
        f32x4 b2 = *(const f32x4*)&Bs[tx + 32][k4 * 4];
        f32x4 b3 = *(const f32x4*)&Bs[tx + 48][k4 * 4];
        #pragma unroll
        for (int e = 0; e < 4; ++e) {
            acc[0][0] += a0[e] * b0[e]; acc[0][1] += a0[e] * b1[e];
            acc[0][2] += a0[e] * b2[e]; acc[0][3] += a0[e] * b3[e];
            acc[1][0] += a1[e] * b0[e]; acc[1][1] += a1[e] * b1[e];
            acc[1][2] += a1[e] * b2[e]; acc[1][3] += a1[e] * b3[e];
            acc[2][0] += a2[e] * b0[e]; acc[2][1] += a2[e] * b1[e];
            acc[2][2] += a2[e] * b2[e]; acc[2][3] += a2[e] * b3[e];
            acc[3][0] += a3[e] * b0[e]; acc[3][1] += a3[e] * b1[e];
            acc[3][2] += a3[e] * b2[e]; acc[3][3] += a3[e] * b3[e];
        }
    }
    #pragma unroll
    for (int i = 0; i < 4; ++i) {
        const int r = ty + i * 16;     // batch b
        #pragma unroll
        for (int j = 0; j < 4; ++j) {
            const int cc = c0 + tx + j * 16;
            Cp[(size_t)r * ldc + cc] = acc[i][j] + (biasp ? biasp[cc] : 0.f);
        }
    }
}

// ---------------------------------------------------------------------------
// Fused per-step kernel v6: grid (64 b, 4 d-quadrants), 512 threads.
// 8-way split-K partial sums; coalesced scores; register fW contraction.
// Hall stored as single bf16 (hi only) for the 2-term output GEMM.
// ---------------------------------------------------------------------------
__global__ __launch_bounds__(512) void k_fused6(
    const u16* __restrict__ uhs16,
    const float* __restrict__ A_w, const float* __restrict__ A_b,
    const float* __restrict__ wahp,  // [8][64][512]
    const float* __restrict__ ghhp,  // [8][64][2048]
    const float* __restrict__ pre_x, // [1920][2048] incl. ih_b+hh_b
    const u16* __restrict__ fW16,    // [64*49][2048] bf16
    float* __restrict__ h_cur, float* __restrict__ c_cur,
    u16* __restrict__ Hall_h,
    float* __restrict__ alphas, int s)
{
    const int bb = blockIdx.x;
    const int qq = blockIdx.y;
    const int tid = threadIdx.x;
    const int lane = tid & 63, w = tid >> 6;
    __shared__ float wah_l[512];
    __shared__ float red[64];
    __shared__ float al[64];
    __shared__ float ghl[512];
    __shared__ float gl[512];

    // ---- independent loads up front ----
    const int gate = tid >> 7, dloc = tid & 127;
    const int jcol = gate * 512 + qq * 128 + dloc;
    float ghv = pre_x[(size_t)(s * 64 + bb) * 2048 + jcol];
    #pragma unroll
    for (int i = 0; i < 8; ++i)
        ghv += ghhp[(size_t)i * 131072 + (size_t)bb * 2048 + jcol];
    float wv = 0.f;
    #pragma unroll
    for (int i = 0; i < 8; ++i)
        wv += wahp[(size_t)i * 32768 + bb * 512 + tid];
    const float cload = c_cur[bb * 512 + qq * 128 + (tid & 127)];

    const int a0 = lane * 8;
    float aw8[8];
    #pragma unroll
    for (int k = 0; k < 8; ++k) aw8[k] = A_w[a0 + k];

    // fW fragment prefetch: thread = (ngf fast, colgroup)
    const int ngf = tid & 7, r = tid >> 3;
    const int gf = r >> 4, oc = r & 15;
    const int jb = gf * 512 + qq * 128 + oc * 8;
    const u16* fb = fW16 + (size_t)bb * NN * 2048 + jb;
    s16x8 pf[7];
    #pragma unroll
    for (int i = 0; i < 7; ++i) {
        const int n = ngf + 8 * i;
        if (n < NN) pf[i] = *(const s16x8*)(fb + (size_t)n * 2048);
        else        pf[i] = (s16x8){0, 0, 0, 0, 0, 0, 0, 0};
    }

    ghl[tid] = ghv;
    wah_l[tid] = wv;
    __syncthreads();

    float wh8[8];
    #pragma unroll
    for (int k = 0; k < 8; ++k) wh8[k] = wah_l[a0 + k];

    // ---- scores: 7 rows per wave, coalesced 16B/lane loads ----
    const u16* ub = uhs16 + (size_t)(bb * NN) * 512 + a0;
    #pragma unroll
    for (int i = 0; i < 7; ++i) {
        const int n = w + 8 * i;
        const int nc = (n < NN) ? n : 0;
        const s16x8 uv = *(const s16x8*)(ub + (size_t)nc * 512);
        float acc = 0.f;
        #pragma unroll
        for (int k = 0; k < 8; ++k)
            acc += aw8[k] * fast_tanh(bf2f((u16)uv[k]) + wh8[k]);
        #pragma unroll
        for (int m = 32; m; m >>= 1) acc += __shfl_xor(acc, m, 64);
        if (lane == 0 && n < NN) red[n] = acc + A_b[0];
    }
    __syncthreads();

    // ---- softmax (wave 0) ----
    if (tid < 64) {
        const float sc = (tid < NN) ? red[tid] : -1e30f;
        float mx = sc;
        #pragma unroll
        for (int m = 32; m; m >>= 1) mx = fmaxf(mx, __shfl_xor(mx, m, 64));
        float e = (tid < NN) ? __expf(sc - mx) : 0.f;
        float sum = e;
        #pragma unroll
        for (int m = 32; m; m >>= 1) sum += __shfl_xor(sum, m, 64);
        const float av = e / sum;
        al[tid] = av;
        if (qq == 0 && tid < NN)
            alphas[(size_t)bb * (TT * NN) + (size_t)s * NN + tid] = av;
    }
    __syncthreads();

    // ---- contraction from prefetched registers; 8-lane shuffle reduce ----
    float a8[8] = {0.f, 0.f, 0.f, 0.f, 0.f, 0.f, 0.f, 0.f};
    #pragma unroll
    for (int i = 0; i < 7; ++i) {
        const int n = ngf + 8 * i;          // al[n>=49] == 0
        const float av = al[n];
        #pragma unroll
        for (int k = 0; k < 8; ++k)
            a8[k] += av * bf2f((u16)pf[i][k]);
    }
    #pragma unroll
    for (int m = 1; m < 8; m <<= 1)
        #pragma unroll
        for (int k = 0; k < 8; ++k)
            a8[k] += __shfl_xor(a8[k], m, 64);
    if (ngf == 0) {
        const int base = gf * 128 + oc * 8;
        #pragma unroll
        for (int k = 0; k < 8; ++k)
            gl[base + k] = a8[k] + ghl[base + k];
    }
    __syncthreads();

    // ---- pointwise LSTM ----
    if (tid < 128) {
        const int dd = qq * 128 + tid;
        const float ig = sigmoidf(gl[tid]);
        const float fg = sigmoidf(gl[128 + tid]);
        const float gg = fast_tanh(gl[256 + tid]);
        const float og = sigmoidf(gl[384 + tid]);
        const float cv = fg * cload + ig * gg;
        const float hv = og * fast_tanh(cv);
        c_cur[bb * 512 + dd] = cv;
        h_cur[bb * 512 + dd] = hv;
        Hall_h[(size_t)(s * 64 + bb) * 512 + dd] = f2bf(hv);
    }
}

// ---------------------------------------------------------------------------
extern "C" void kernel_launch(void* const* d_in, const int* in_sizes, int n_in,
                              void* d_out, int out_size, void* d_ws, size_t ws_size,
                              hipStream_t stream)
{
    const float* features = (const float*)d_in[0];
    const int*   captions = (const int*)d_in[1];
    const float* emb      = (const float*)d_in[2];
    const float* U_w      = (const float*)d_in[3];
    const float* U_b      = (const float*)d_in[4];
    const float* W_w      = (const float*)d_in[5];
    const float* W_b      = (const float*)d_in[6];
    const float* A_w      = (const float*)d_in[7];
    const float* A_b      = (const float*)d_in[8];
    const float* iH_w     = (const float*)d_in[9];
    const float* iH_b     = (const float*)d_in[10];
    const float* iC_w     = (const float*)d_in[11];
    const float* iC_b     = (const float*)d_in[12];
    const float* ih_w     = (const float*)d_in[13];
    const float* ih_b     = (const float*)d_in[14];
    const float* hh_w     = (const float*)d_in[15];
    const float* hh_b     = (const float*)d_in[16];
    const float* fcn_w    = (const float*)d_in[17];
    const float* fcn_b    = (const float*)d_in[18];

    float* out    = (float*)d_out;
    float* alphas = out + (size_t)B * TT * VOC;

    float* ws     = (float*)d_ws;
    // layout (float offsets); total <= 16,730,112 floats = 66.9 MB
    u16*  fW16    = (u16*)ws;                      // 3,211,264 f
    u16*  uhs16   = (u16*)(ws + 3211264);          //   802,816 f
    float* pre_x  = ws + 4014080;                  // 3,932,160 f
    u16*  Hall_h  = (u16*)(ws + 7946240);          //   491,520 f
    float* h_cur  = ws + 8929280;                  //    32,768
    float* c_cur  = ws + 8962048;                  //    32,768
    float* wahp   = ws + 8994816;                  //   262,144 (8*64*512)
    float* ghhp   = ws + 9256960;                  // 1,048,576 (8*64*2048)
    float* bias2  = ws + 10305536;                 //     2,048
    u16*  fhi     = (u16*)(ws + 10307584);         // 3,211,264 f
    u16*  flo     = (u16*)(ws + 13518848);         // 3,211,264 f
    // aliases over dead producers:
    float* pbuf   = ws;                            // init partials (in fW16 region)
    float* mean_f = ws + 1048576;                  // after pbuf, still in fW16 region
    u16*  ihw_h   = (u16*)pre_x;                   // pre-split ih_w hi (dead before mfma_prex)
    u16*  ihw_l   = (u16*)(ws + 6111232);          // pre-split ih_w lo
    u16*  fcnw_h  = fhi;                           // fcn_w split (after mfma_cat2)
    u16*  fcnw_l  = flo;

    // init hidden state
    k_mean<<<64, 256, 0, stream>>>(features, mean_f);
    k_init_partial<<<dim3(16, 16), 256, 0, stream>>>(mean_f, iH_w, iC_w, pbuf);
    k_init_reduce<<<256, 256, 0, stream>>>(pbuf, iH_b, iC_b, h_cur, c_cur);

    // hoisted precomputes
    k_bias2<<<8, 256, 0, stream>>>(ih_b, hh_b, bias2);
    k_split<<<6272, 256, 0, stream>>>(features, fhi, flo, B * NN * ENC);
    k_splitW<<<2048, 256, 0, stream>>>(ih_w, ihw_h, ihw_l);
    // combined u_hs+fW GEMM: [3136 x 2560] over K=2048 (XCD-swizzled)
    mfma_cat2<<<dim3(20, 25), 512, 0, stream>>>(fhi, flo, U_w, U_b, ihw_h, ihw_l,
                                                uhs16, fW16, B * NN);
    // fcn_w split (fhi/flo dead after mfma_cat2)
    k_split<<<5000, 256, 0, stream>>>(fcn_w, fcnw_h, fcnw_l, VOC * DEC);
    // pre_x with fused embedding gather (overwrites dead ihw buffers)
    mfma_prex<<<dim3(16, 15), 512, 0, stream>>>(captions, emb, ih_w, bias2, pre_x);

    // recurrence
    k_hw8<<<dim3(40, 8), 256, 0, stream>>>(h_cur, W_w, W_b, hh_w, wahp, ghhp);
    for (int s = 0; s < TT; ++s) {
        k_fused6<<<dim3(64, 4), 512, 0, stream>>>(uhs16, A_w, A_b, wahp, ghhp, pre_x, fW16,
                                                  h_cur, c_cur, Hall_h, alphas, s);
        if (s < TT - 1)
            k_hw8<<<dim3(40, 8), 256, 0, stream>>>(h_cur, W_w, W_b, hh_w, wahp, ghhp);
    }

    // 2-term output projection: A = Hall bf16, B = fcn_w hi/lo (XCD-swizzled)
    mfma_pre2<<<dim3(79, 15), 512, 0, stream>>>(Hall_h, fcnw_h, fcnw_l, fcn_b,
                                                out, TT * B, VOC);
}

// Round 11
// 846.479 us; speedup vs baseline: 1.0970x; 1.0589x over previous
//
#include <hip/hip_runtime.h>
#include <math.h>

// Problem constants
#define B 64
#define NN 49
#define ENC 2048
#define DEC 512
#define ATT 512
#define EMB 300
#define VOC 10000
#define TT 30

typedef __attribute__((ext_vector_type(4))) float f32x4;
typedef __attribute__((ext_vector_type(4))) short s16x4;
typedef __attribute__((ext_vector_type(8))) short s16x8;
typedef unsigned short u16;

__device__ __forceinline__ float fast_tanh(float x) {
    float e = __expf(2.f * x);
    return 1.f - 2.f / (e + 1.f);
}
__device__ __forceinline__ float sigmoidf(float x) {
    return 1.f / (1.f + __expf(-x));
}
__device__ __forceinline__ u16 f2bf(float x) {
    unsigned u = __float_as_uint(x);
    unsigned r = u + 0x7FFFu + ((u >> 16) & 1u);
    return (u16)(r >> 16);
}
__device__ __forceinline__ float bf2f(u16 u) {
    return __uint_as_float((unsigned)u << 16);
}
__device__ __forceinline__ void split_bf16(float x, short& hi, short& lo) {
    u16 h = f2bf(x);
    float hf = __uint_as_float((unsigned)h << 16);
    hi = (short)h;
    lo = (short)f2bf(x - hf);
}
__device__ __forceinline__ s16x8 ld8(const short* p) {
    s16x4 a = *(const s16x4*)p;
    s16x4 b = *(const s16x4*)(p + 4);
    return __builtin_shufflevector(a, b, 0, 1, 2, 3, 4, 5, 6, 7);
}
// bijective XCD swizzle (m204)
__device__ __forceinline__ int xcd_swz(int bid, int nwg) {
    const int q = nwg >> 3, r = nwg & 7;
    const int xcd = bid & 7, idx = bid >> 3;
    return ((xcd < r) ? xcd * (q + 1) : r * (q + 1) + (xcd - r) * q) + idx;
}

// ---------------------------------------------------------------------------
// mfma_cat3: 2-term GEMM. A = features hi (bf16), B = [U_w on-the-fly hi/lo ;
// pre-split ih_w hi/lo]. D = A_h*(B_h + B_l). K=2048, N=2560.
// col<512 -> uhs16 (+U_b); col>=512 -> fW16.
// ---------------------------------------------------------------------------
__global__ __launch_bounds__(512) void mfma_cat3(
    const u16* __restrict__ fhi,
    const float* __restrict__ U_w, const float* __restrict__ U_b,
    const u16* __restrict__ ihw_h, const u16* __restrict__ ihw_l,
    u16* __restrict__ uhs16, u16* __restrict__ fW16, int M)
{
    __shared__ short Ah[128][40];
    __shared__ short Bh[128][40];
    __shared__ short Bl[128][40];

    const int tid = threadIdx.x;
    const int nwg = gridDim.x * gridDim.y;
    const int swz = xcd_swz(blockIdx.y * gridDim.x + blockIdx.x, nwg);
    const int m0 = (swz / gridDim.x) * 128;
    const int n0 = (swz % gridDim.x) * 128;
    const int wid = tid >> 6, lane = tid & 63;
    const int wm = wid >> 2, wn = wid & 3;
    const int lrow = lane & 15;
    const int lko = (lane >> 4) * 8;
    const int srow = tid >> 2;
    const int sk = (tid & 3) * 8;

    const int gc = n0 + srow;
    const int gr = m0 + srow;
    const u16* ahp = fhi + (size_t)gr * 2048;

    f32x4 acc[4][2];
    #pragma unroll
    for (int i = 0; i < 4; ++i)
        #pragma unroll
        for (int j = 0; j < 2; ++j)
            acc[i][j] = (f32x4){0.f, 0.f, 0.f, 0.f};

    for (int kt = 0; kt < 64; ++kt) {
        const int kb0 = kt * 32 + sk;
        {
            s16x8 vh = {0,0,0,0,0,0,0,0};
            if (gr < M) vh = *(const s16x8*)(ahp + kb0);
            *(s16x8*)&Ah[srow][sk] = vh;
        }
        if (n0 < 512) {
            const float* bp = U_w + (size_t)gc * 2048;
            float4 x0 = *(const float4*)(bp + kb0);
            float4 x1 = *(const float4*)(bp + kb0 + 4);
            float v[8] = {x0.x, x0.y, x0.z, x0.w, x1.x, x1.y, x1.z, x1.w};
            s16x4 h0, h1, l0, l1;
            #pragma unroll
            for (int j = 0; j < 4; ++j) { short h, l; split_bf16(v[j], h, l); h0[j] = h; l0[j] = l; }
            #pragma unroll
            for (int j = 0; j < 4; ++j) { short h, l; split_bf16(v[4 + j], h, l); h1[j] = h; l1[j] = l; }
            *(s16x4*)&Bh[srow][sk] = h0; *(s16x4*)&Bh[srow][sk + 4] = h1;
            *(s16x4*)&Bl[srow][sk] = l0; *(s16x4*)&Bl[srow][sk + 4] = l1;
        } else {
            *(s16x8*)&Bh[srow][sk] = *(const s16x8*)(ihw_h + (size_t)(gc - 512) * 2048 + kb0);
            *(s16x8*)&Bl[srow][sk] = *(const s16x8*)(ihw_l + (size_t)(gc - 512) * 2048 + kb0);
        }
        __syncthreads();

        s16x8 bh[2], bl[2];
        #pragma unroll
        for (int nr = 0; nr < 2; ++nr) {
            const int col = wn * 32 + nr * 16 + lrow;
            bh[nr] = ld8(&Bh[col][lko]);
            bl[nr] = ld8(&Bl[col][lko]);
        }
        #pragma unroll
        for (int mr = 0; mr < 4; ++mr) {
            const int row = wm * 64 + mr * 16 + lrow;
            s16x8 ah = ld8(&Ah[row][lko]);
            #pragma unroll
            for (int nr = 0; nr < 2; ++nr) {
                acc[mr][nr] = __builtin_amdgcn_mfma_f32_16x16x32_bf16(ah, bh[nr], acc[mr][nr], 0, 0, 0);
                acc[mr][nr] = __builtin_amdgcn_mfma_f32_16x16x32_bf16(ah, bl[nr], acc[mr][nr], 0, 0, 0);
            }
        }
        __syncthreads();
    }

    #pragma unroll
    for (int mr = 0; mr < 4; ++mr) {
        #pragma unroll
        for (int nr = 0; nr < 2; ++nr) {
            #pragma unroll
            for (int r = 0; r < 4; ++r) {
                const int row = m0 + wm * 64 + mr * 16 + (lane >> 4) * 4 + r;
                const int col = n0 + wn * 32 + nr * 16 + (lane & 15);
                if (row < M) {
                    if (col < 512)
                        uhs16[(size_t)row * 512 + col] = f2bf(acc[mr][nr][r] + U_b[col]);
                    else
                        fW16[(size_t)row * 2048 + (col - 512)] = f2bf(acc[mr][nr][r]);
                }
            }
        }
    }
}

// ---------------------------------------------------------------------------
// mfma_prex: pre_x = gather(emb, captions) @ ih_w[:, :300]^T + bias2. 3-term.
// ---------------------------------------------------------------------------
__global__ __launch_bounds__(512) void mfma_prex(
    const int* __restrict__ cap,
    const float* __restrict__ emb,
    const float* __restrict__ ih_w,
    const float* __restrict__ bias2,
    float* __restrict__ pre_x)
{
    __shared__ short Ah[128][40];
    __shared__ short Al[128][40];
    __shared__ short Bh[128][40];
    __shared__ short Bl[128][40];

    const int tid = threadIdx.x;
    const int m0 = blockIdx.y * 128, n0 = blockIdx.x * 128;
    const int wid = tid >> 6, lane = tid & 63;
    const int wm = wid >> 2, wn = wid & 3;
    const int lrow = lane & 15;
    const int lko = (lane >> 4) * 8;
    const int srow = tid >> 2;
    const int sk = (tid & 3) * 8;

    const int gr = m0 + srow;
    const int tt = gr >> 6, bbs = gr & 63;
    const float* ap = emb + (size_t)cap[bbs * 31 + tt] * 300;
    const int gc = n0 + srow;
    const float* bp = ih_w + (size_t)gc * 2348;

    f32x4 acc[4][2];
    #pragma unroll
    for (int i = 0; i < 4; ++i)
        #pragma unroll
        for (int j = 0; j < 2; ++j)
            acc[i][j] = (f32x4){0.f, 0.f, 0.f, 0.f};

    for (int kt = 0; kt < 10; ++kt) {
        const int kb0 = kt * 32 + sk;
        {
            float v[8];
            if (kb0 + 7 < 300) {
                float4 x0 = *(const float4*)(ap + kb0);
                float4 x1 = *(const float4*)(ap + kb0 + 4);
                v[0] = x0.x; v[1] = x0.y; v[2] = x0.z; v[3] = x0.w;
                v[4] = x1.x; v[5] = x1.y; v[6] = x1.z; v[7] = x1.w;
            } else {
                #pragma unroll
                for (int j = 0; j < 8; ++j)
                    v[j] = (kb0 + j < 300) ? ap[kb0 + j] : 0.f;
            }
            s16x4 h0, h1, l0, l1;
            #pragma unroll
            for (int j = 0; j < 4; ++j) { short h, l; split_bf16(v[j], h, l); h0[j] = h; l0[j] = l; }
            #pragma unroll
            for (int j = 0; j < 4; ++j) { short h, l; split_bf16(v[4 + j], h, l); h1[j] = h; l1[j] = l; }
            *(s16x4*)&Ah[srow][sk] = h0; *(s16x4*)&Ah[srow][sk + 4] = h1;
            *(s16x4*)&Al[srow][sk] = l0; *(s16x4*)&Al[srow][sk + 4] = l1;
        }
        {
            float v[8];
            if (kb0 + 7 < 300) {
                float4 x0 = *(const float4*)(bp + kb0);
                float4 x1 = *(const float4*)(bp + kb0 + 4);
                v[0] = x0.x; v[1] = x0.y; v[2] = x0.z; v[3] = x0.w;
                v[4] = x1.x; v[5] = x1.y; v[6] = x1.z; v[7] = x1.w;
            } else {
                #pragma unroll
                for (int j = 0; j < 8; ++j)
                    v[j] = (kb0 + j < 300) ? bp[kb0 + j] : 0.f;
            }
            s16x4 h0, h1, l0, l1;
            #pragma unroll
            for (int j = 0; j < 4; ++j) { short h, l; split_bf16(v[j], h, l); h0[j] = h; l0[j] = l; }
            #pragma unroll
            for (int j = 0; j < 4; ++j) { short h, l; split_bf16(v[4 + j], h, l); h1[j] = h; l1[j] = l; }
            *(s16x4*)&Bh[srow][sk] = h0; *(s16x4*)&Bh[srow][sk + 4] = h1;
            *(s16x4*)&Bl[srow][sk] = l0; *(s16x4*)&Bl[srow][sk + 4] = l1;
        }
        __syncthreads();

        s16x8 bh[2], bl[2];
        #pragma unroll
        for (int nr = 0; nr < 2; ++nr) {
            const int col = wn * 32 + nr * 16 + lrow;
            bh[nr] = ld8(&Bh[col][lko]);
            bl[nr] = ld8(&Bl[col][lko]);
        }
        #pragma unroll
        for (int mr = 0; mr < 4; ++mr) {
            const int row = wm * 64 + mr * 16 + lrow;
            s16x8 ah = ld8(&Ah[row][lko]);
            s16x8 al = ld8(&Al[row][lko]);
            #pragma unroll
            for (int nr = 0; nr < 2; ++nr) {
                acc[mr][nr] = __builtin_amdgcn_mfma_f32_16x16x32_bf16(ah, bh[nr], acc[mr][nr], 0, 0, 0);
                acc[mr][nr] = __builtin_amdgcn_mfma_f32_16x16x32_bf16(ah, bl[nr], acc[mr][nr], 0, 0, 0);
                acc[mr][nr] = __builtin_amdgcn_mfma_f32_16x16x32_bf16(al, bh[nr], acc[mr][nr], 0, 0, 0);
            }
        }
        __syncthreads();
    }

    #pragma unroll
    for (int mr = 0; mr < 4; ++mr) {
        #pragma unroll
        for (int nr = 0; nr < 2; ++nr) {
            #pragma unroll
            for (int r = 0; r < 4; ++r) {
                const int row = m0 + wm * 64 + mr * 16 + (lane >> 4) * 4 + r;
                const int col = n0 + wn * 32 + nr * 16 + (lane & 15);
                pre_x[(size_t)row * 2048 + col] = acc[mr][nr][r] + bias2[col];
            }
        }
    }
}

// ---------------------------------------------------------------------------
// mfma_pre3: pure-bf16 output GEMM. A = Hall hi, B = fcn_w hi. K=512.
// preds scatter + bias, XCD-swizzled.
// ---------------------------------------------------------------------------
__global__ __launch_bounds__(512) void mfma_pre3(
    const u16* __restrict__ Ahg,
    const u16* __restrict__ Bhg,
    const float* __restrict__ bias,
    float* __restrict__ C, int M, int N)
{
    __shared__ short Ah[128][40];
    __shared__ short Bh[128][40];

    const int tid = threadIdx.x;
    const int nwg = gridDim.x * gridDim.y;
    const int swz = xcd_swz(blockIdx.y * gridDim.x + blockIdx.x, nwg);
    const int m0 = (swz / gridDim.x) * 128;
    const int n0 = (swz % gridDim.x) * 128;
    const int wid = tid >> 6, lane = tid & 63;
    const int wm = wid >> 2, wn = wid & 3;
    const int lrow = lane & 15;
    const int lko = (lane >> 4) * 8;
    const int srow = tid >> 2;
    const int sk = (tid & 3) * 8;

    f32x4 acc[4][2];
    #pragma unroll
    for (int i = 0; i < 4; ++i)
        #pragma unroll
        for (int j = 0; j < 2; ++j)
            acc[i][j] = (f32x4){0.f, 0.f, 0.f, 0.f};

    for (int kt = 0; kt < 16; ++kt) {
        const int kb0 = kt * 32 + sk;
        {
            const int gr = m0 + srow;
            s16x8 vh = {0,0,0,0,0,0,0,0};
            if (gr < M) vh = *(const s16x8*)(Ahg + (size_t)gr * 512 + kb0);
            *(s16x8*)&Ah[srow][sk] = vh;
        }
        {
            const int gc = n0 + srow;
            s16x8 vh = {0,0,0,0,0,0,0,0};
            if (gc < N) vh = *(const s16x8*)(Bhg + (size_t)gc * 512 + kb0);
            *(s16x8*)&Bh[srow][sk] = vh;
        }
        __syncthreads();

        s16x8 bh[2];
        #pragma unroll
        for (int nr = 0; nr < 2; ++nr) {
            const int col = wn * 32 + nr * 16 + lrow;
            bh[nr] = ld8(&Bh[col][lko]);
        }
        #pragma unroll
        for (int mr = 0; mr < 4; ++mr) {
            const int row = wm * 64 + mr * 16 + lrow;
            s16x8 ah = ld8(&Ah[row][lko]);
            #pragma unroll
            for (int nr = 0; nr < 2; ++nr)
                acc[mr][nr] = __builtin_amdgcn_mfma_f32_16x16x32_bf16(ah, bh[nr], acc[mr][nr], 0, 0, 0);
        }
        __syncthreads();
    }

    #pragma unroll
    for (int mr = 0; mr < 4; ++mr) {
        #pragma unroll
        for (int nr = 0; nr < 2; ++nr) {
            #pragma unroll
            for (int r = 0; r < 4; ++r) {
                const int row = m0 + wm * 64 + mr * 16 + (lane >> 4) * 4 + r;
                const int col = n0 + wn * 32 + nr * 16 + (lane & 15);
                if (row < M && col < N) {
                    const float val = acc[mr][nr][r] + bias[col];
                    const int t = row >> 6, bb = row & 63;
                    C[(size_t)bb * (TT * VOC) + (size_t)t * VOC + col] = val;
                }
            }
        }
    }
}

__global__ __launch_bounds__(256) void k_mean(const float* __restrict__ f,
                                              float* __restrict__ mean_f)
{
    const int b = blockIdx.x;
    for (int e = threadIdx.x; e < ENC; e += 256) {
        float s = 0.f;
        for (int n = 0; n < NN; ++n) s += f[(size_t)(b * NN + n) * ENC + e];
        mean_f[(size_t)b * ENC + e] = s * (1.f / 49.f);
    }
}

__global__ __launch_bounds__(256) void k_init_partial(
    const float* __restrict__ mean_f,
    const float* __restrict__ iH_w, const float* __restrict__ iC_w,
    float* __restrict__ pbuf)
{
    const int tid = threadIdx.x;
    const int tx = tid & 15, ty = tid >> 4;
    const int n0 = blockIdx.x * 64;
    const int ks = blockIdx.y;
    __shared__ float As[16][64];
    __shared__ float Bs[16][64];
    float acc[4][4] = {};
    const int lrow = tid >> 2;
    const int lk = (tid & 3) * 4;
    for (int c = 0; c < 8; ++c) {
        const int kk = ks * 128 + c * 16 + lk;
        float4 av = *(const float4*)(mean_f + (size_t)lrow * 2048 + kk);
        const int col = n0 + lrow;
        const float* wp = (col < 512) ? (iH_w + (size_t)col * 2048)
                                      : (iC_w + (size_t)(col - 512) * 2048);
        float4 bv = *(const float4*)(wp + kk);
        As[lk + 0][lrow] = av.x; As[lk + 1][lrow] = av.y;
        As[lk + 2][lrow] = av.z; As[lk + 3][lrow] = av.w;
        Bs[lk + 0][lrow] = bv.x; Bs[lk + 1][lrow] = bv.y;
        Bs[lk + 2][lrow] = bv.z; Bs[lk + 3][lrow] = bv.w;
        __syncthreads();
        #pragma unroll
        for (int k = 0; k < 16; ++k) {
            float4 a = *(const float4*)&As[k][ty * 4];
            float4 b = *(const float4*)&Bs[k][tx * 4];
            acc[0][0] += a.x * b.x; acc[0][1] += a.x * b.y; acc[0][2] += a.x * b.z; acc[0][3] += a.x * b.w;
            acc[1][0] += a.y * b.x; acc[1][1] += a.y * b.y; acc[1][2] += a.y * b.z; acc[1][3] += a.y * b.w;
            acc[2][0] += a.z * b.x; acc[2][1] += a.z * b.y; acc[2][2] += a.z * b.z; acc[2][3] += a.z * b.w;
            acc[3][0] += a.w * b.x; acc[3][1] += a.w * b.y; acc[3][2] += a.w * b.z; acc[3][3] += a.w * b.w;
        }
        __syncthreads();
    }
    #pragma unroll
    for (int i = 0; i < 4; ++i) {
        const int r = ty * 4 + i;
        #pragma unroll
        for (int j = 0; j < 4; ++j)
            pbuf[(size_t)(ks * 64 + r) * 1024 + n0 + tx * 4 + j] = acc[i][j];
    }
}

__global__ __launch_bounds__(256) void k_init_reduce(
    const float* __restrict__ pbuf,
    const float* __restrict__ iH_b, const float* __restrict__ iC_b,
    float* __restrict__ h_cur, float* __restrict__ c_cur)
{
    const int idx = blockIdx.x * 256 + threadIdx.x;
    const int r = idx >> 10, c = idx & 1023;
    float s = 0.f;
    #pragma unroll
    for (int ks = 0; ks < 16; ++ks) s += pbuf[(size_t)(ks * 64 + r) * 1024 + c];
    if (c < 512) h_cur[r * 512 + c] = s + iH_b[c];
    else         c_cur[r * 512 + (c - 512)] = s + iC_b[c - 512];
}

// ---------------------------------------------------------------------------
// k_prep: merged preprocessing. blocks [0,2048): ih_w slice split hi/lo;
// [2048,4548): fcn_w hi cast; [4548,6116): features hi cast; [6116]: bias2.
// ---------------------------------------------------------------------------
__global__ __launch_bounds__(256) void k_prep(
    const float* __restrict__ ih_w, const float* __restrict__ fcn_w,
    const float* __restrict__ features,
    const float* __restrict__ ih_b, const float* __restrict__ hh_b,
    u16* __restrict__ ihw_h, u16* __restrict__ ihw_l,
    u16* __restrict__ fcnw_h, u16* __restrict__ fhi,
    float* __restrict__ bias2)
{
    const int bid = blockIdx.x;
    const int tid = threadIdx.x;
    if (bid < 2048) {
        const float* src = ih_w + (size_t)bid * 2348 + 300;
        u16* hp = ihw_h + (size_t)bid * 2048;
        u16* lp = ihw_l + (size_t)bid * 2048;
        const int c = tid * 8;
        #pragma unroll
        for (int g = 0; g < 2; ++g) {
            f32x4 v = *(const f32x4*)(src + c + g * 4);
            s16x4 h4, l4;
            #pragma unroll
            for (int j = 0; j < 4; ++j) { short h, l; split_bf16(v[j], h, l); h4[j] = h; l4[j] = l; }
            *(s16x4*)(hp + c + g * 4) = h4;
            *(s16x4*)(lp + c + g * 4) = l4;
        }
    } else if (bid < 4548) {
        const int i = (bid - 2048) * 2048 + tid * 8;
        #pragma unroll
        for (int g = 0; g < 2; ++g) {
            f32x4 v = *(const f32x4*)(fcn_w + i + g * 4);
            s16x4 h4;
            #pragma unroll
            for (int j = 0; j < 4; ++j) h4[j] = (short)f2bf(v[j]);
            *(s16x4*)(fcnw_h + i + g * 4) = h4;
        }
    } else if (bid < 6116) {
        const int i = (bid - 4548) * 4096 + tid * 16;
        #pragma unroll
        for (int g = 0; g < 4; ++g) {
            f32x4 v = *(const f32x4*)(features + i + g * 4);
            s16x4 h4;
            #pragma unroll
            for (int j = 0; j < 4; ++j) h4[j] = (short)f2bf(v[j]);
            *(s16x4*)(fhi + i + g * 4) = h4;
        }
    } else {
        const int j = tid * 8;
        #pragma unroll
        for (int k = 0; k < 8; ++k) bias2[j + k] = ih_b[j + k] + hh_b[j + k];
    }
}

// ---------------------------------------------------------------------------
// wah/ghh split-K GEMV: grid (40, 8), 256 thr, K-slice 64, conflict-free LDS.
// ---------------------------------------------------------------------------
__global__ __launch_bounds__(256) void k_hw8(
    const float* __restrict__ h,
    const float* __restrict__ W_w, const float* __restrict__ W_b,
    const float* __restrict__ hh_w,
    float* __restrict__ wahp, float* __restrict__ ghhp)
{
    const int tid = threadIdx.x;
    const int tx = tid & 15, ty = tid >> 4;
    const int n0 = blockIdx.x * 64;
    const int ks = blockIdx.y;
    const float* Bp; const float* biasp; float* Cp; int c0, ldc;
    if (n0 < 512) { Bp = W_w + (size_t)n0 * 512; biasp = (ks == 0) ? W_b : nullptr; Cp = wahp + (size_t)ks * 32768; c0 = n0; ldc = 512; }
    else { Bp = hh_w + (size_t)(n0 - 512) * 512; biasp = nullptr; Cp = ghhp + (size_t)ks * 131072; c0 = n0 - 512; ldc = 2048; }

    __shared__ float As[64][68];
    __shared__ float Bs[64][68];
    float acc[4][4] = {};
    const int rt = tid >> 2;
    const int cs = (tid & 3) * 16;
    const int kbase = ks * 64;

    #pragma unroll
    for (int i = 0; i < 4; ++i) {
        const int c = cs + i * 4;
        *(f32x4*)&As[rt][c] = *(const f32x4*)(h + (size_t)rt * 512 + kbase + c);
        *(f32x4*)&Bs[rt][c] = *(const f32x4*)(Bp + (size_t)rt * 512 + kbase + c);
    }
    __syncthreads();
    #pragma unroll 4
    for (int k4 = 0; k4 < 16; ++k4) {
        f32x4 a0 = *(const f32x4*)&As[ty + 0][k4 * 4];
        f32x4 a1 = *(const f32x4*)&As[ty + 16][k4 * 4];
        f32x4 a2 = *(const f32x4*)&As[ty + 32][k4 * 4];
        f32x4 a3 = *(const f32x4*)&As[ty + 48][k4 * 4];
        f32x4 b0 = *(const f32x4*)&Bs[tx + 0][k4 * 4];
        f32x4 b1 = *(const f32x4*)&Bs[tx + 16][k4 * 4];
        f32x4 b2 = *(const f32x4*)&Bs[tx + 32][k4 * 4];
        f32x4 b3 = *(const f32x4*)&Bs[tx + 48][k4 * 4];
        #pragma unroll
        for (int e = 0; e < 4; ++e) {
            acc[0][0] += a0[e] * b0[e]; acc[0][1] += a0[e] * b1[e];
            acc[0][2] += a0[e] * b2[e]; acc[0][3] += a0[e] * b3[e];
            acc[1][0] += a1[e] * b0[e]; acc[1][1] += a1[e] * b1[e];
            acc[1][2] += a1[e] * b2[e]; acc[1][3] += a1[e] * b3[e];
            acc[2][0] += a2[e] * b0[e]; acc[2][1] += a2[e] * b1[e];
            acc[2][2] += a2[e] * b2[e]; acc[2][3] += a2[e] * b3[e];
            acc[3][0] += a3[e] * b0[e]; acc[3][1] += a3[e] * b1[e];
            acc[3][2] += a3[e] * b2[e]; acc[3][3] += a3[e] * b3[e];
        }
    }
    #pragma unroll
    for (int i = 0; i < 4; ++i) {
        const int r = ty + i * 16;
        #pragma unroll
        for (int j = 0; j < 4; ++j) {
            const int cc = c0 + tx + j * 16;
            Cp[(size_t)r * ldc + cc] = acc[i][j] + (biasp ? biasp[cc] : 0.f);
        }
    }
}

// ---------------------------------------------------------------------------
// Fused per-step kernel: grid (64 b, 4 d-quadrants), 512 threads.
// ---------------------------------------------------------------------------
__global__ __launch_bounds__(512) void k_fused6(
    const u16* __restrict__ uhs16,
    const float* __restrict__ A_w, const float* __restrict__ A_b,
    const float* __restrict__ wahp,  // [8][64][512]
    const float* __restrict__ ghhp,  // [8][64][2048]
    const float* __restrict__ pre_x, // [1920][2048] incl. ih_b+hh_b
    const u16* __restrict__ fW16,    // [64*49][2048] bf16
    float* __restrict__ h_cur, float* __restrict__ c_cur,
    u16* __restrict__ Hall_h,
    float* __restrict__ alphas, int s)
{
    const int bb = blockIdx.x;
    const int qq = blockIdx.y;
    const int tid = threadIdx.x;
    const int lane = tid & 63, w = tid >> 6;
    __shared__ float wah_l[512];
    __shared__ float red[64];
    __shared__ float al[64];
    __shared__ float ghl[512];
    __shared__ float gl[512];

    const int gate = tid >> 7, dloc = tid & 127;
    const int jcol = gate * 512 + qq * 128 + dloc;
    float ghv = pre_x[(size_t)(s * 64 + bb) * 2048 + jcol];
    #pragma unroll
    for (int i = 0; i < 8; ++i)
        ghv += ghhp[(size_t)i * 131072 + (size_t)bb * 2048 + jcol];
    float wv = 0.f;
    #pragma unroll
    for (int i = 0; i < 8; ++i)
        wv += wahp[(size_t)i * 32768 + bb * 512 + tid];
    const float cload = c_cur[bb * 512 + qq * 128 + (tid & 127)];

    const int a0 = lane * 8;
    float aw8[8];
    #pragma unroll
    for (int k = 0; k < 8; ++k) aw8[k] = A_w[a0 + k];

    const int ngf = tid & 7, r = tid >> 3;
    const int gf = r >> 4, oc = r & 15;
    const int jb = gf * 512 + qq * 128 + oc * 8;
    const u16* fb = fW16 + (size_t)bb * NN * 2048 + jb;
    s16x8 pf[7];
    #pragma unroll
    for (int i = 0; i < 7; ++i) {
        const int n = ngf + 8 * i;
        if (n < NN) pf[i] = *(const s16x8*)(fb + (size_t)n * 2048);
        else        pf[i] = (s16x8){0, 0, 0, 0, 0, 0, 0, 0};
    }

    ghl[tid] = ghv;
    wah_l[tid] = wv;
    __syncthreads();

    float wh8[8];
    #pragma unroll
    for (int k = 0; k < 8; ++k) wh8[k] = wah_l[a0 + k];

    const u16* ub = uhs16 + (size_t)(bb * NN) * 512 + a0;
    #pragma unroll
    for (int i = 0; i < 7; ++i) {
        const int n = w + 8 * i;
        const int nc = (n < NN) ? n : 0;
        const s16x8 uv = *(const s16x8*)(ub + (size_t)nc * 512);
        float acc = 0.f;
        #pragma unroll
        for (int k = 0; k < 8; ++k)
            acc += aw8[k] * fast_tanh(bf2f((u16)uv[k]) + wh8[k]);
        #pragma unroll
        for (int m = 32; m; m >>= 1) acc += __shfl_xor(acc, m, 64);
        if (lane == 0 && n < NN) red[n] = acc + A_b[0];
    }
    __syncthreads();

    if (tid < 64) {
        const float sc = (tid < NN) ? red[tid] : -1e30f;
        float mx = sc;
        #pragma unroll
        for (int m = 32; m; m >>= 1) mx = fmaxf(mx, __shfl_xor(mx, m, 64));
        float e = (tid < NN) ? __expf(sc - mx) : 0.f;
        float sum = e;
        #pragma unroll
        for (int m = 32; m; m >>= 1) sum += __shfl_xor(sum, m, 64);
        const float av = e / sum;
        al[tid] = av;
        if (qq == 0 && tid < NN)
            alphas[(size_t)bb * (TT * NN) + (size_t)s * NN + tid] = av;
    }
    __syncthreads();

    float a8[8] = {0.f, 0.f, 0.f, 0.f, 0.f, 0.f, 0.f, 0.f};
    #pragma unroll
    for (int i = 0; i < 7; ++i) {
        const int n = ngf + 8 * i;
        const float av = al[n];
        #pragma unroll
        for (int k = 0; k < 8; ++k)
            a8[k] += av * bf2f((u16)pf[i][k]);
    }
    #pragma unroll
    for (int m = 1; m < 8; m <<= 1)
        #pragma unroll
        for (int k = 0; k < 8; ++k)
            a8[k] += __shfl_xor(a8[k], m, 64);
    if (ngf == 0) {
        const int base = gf * 128 + oc * 8;
        #pragma unroll
        for (int k = 0; k < 8; ++k)
            gl[base + k] = a8[k] + ghl[base + k];
    }
    __syncthreads();

    if (tid < 128) {
        const int dd = qq * 128 + tid;
        const float ig = sigmoidf(gl[tid]);
        const float fg = sigmoidf(gl[128 + tid]);
        const float gg = fast_tanh(gl[256 + tid]);
        const float og = sigmoidf(gl[384 + tid]);
        const float cv = fg * cload + ig * gg;
        const float hv = og * fast_tanh(cv);
        c_cur[bb * 512 + dd] = cv;
        h_cur[bb * 512 + dd] = hv;
        Hall_h[(size_t)(s * 64 + bb) * 512 + dd] = f2bf(hv);
    }
}

// ---------------------------------------------------------------------------
extern "C" void kernel_launch(void* const* d_in, const int* in_sizes, int n_in,
                              void* d_out, int out_size, void* d_ws, size_t ws_size,
                              hipStream_t stream)
{
    const float* features = (const float*)d_in[0];
    const int*   captions = (const int*)d_in[1];
    const float* emb      = (const float*)d_in[2];
    const float* U_w      = (const float*)d_in[3];
    const float* U_b      = (const float*)d_in[4];
    const float* W_w      = (const float*)d_in[5];
    const float* W_b      = (const float*)d_in[6];
    const float* A_w      = (const float*)d_in[7];
    const float* A_b      = (const float*)d_in[8];
    const float* iH_w     = (const float*)d_in[9];
    const float* iH_b     = (const float*)d_in[10];
    const float* iC_w     = (const float*)d_in[11];
    const float* iC_b     = (const float*)d_in[12];
    const float* ih_w     = (const float*)d_in[13];
    const float* ih_b     = (const float*)d_in[14];
    const float* hh_w     = (const float*)d_in[15];
    const float* hh_b     = (const float*)d_in[16];
    const float* fcn_w    = (const float*)d_in[17];
    const float* fcn_b    = (const float*)d_in[18];

    float* out    = (float*)d_out;
    float* alphas = out + (size_t)B * TT * VOC;

    float* ws     = (float*)d_ws;
    // layout (float offsets); total 15,587,328 f = 62.3 MB
    u16*  fW16    = (u16*)ws;                      // [0, 3211264)
    u16*  uhs16   = (u16*)(ws + 3211264);          // [3211264, 4014080)
    float* pre_x  = ws + 4014080;                  // [4014080, 7946240)
    u16*  Hall_h  = (u16*)(ws + 7946240);          // [7946240, 8437760)
    float* h_cur  = ws + 8437760;                  // 32,768
    float* c_cur  = ws + 8470528;                  // 32,768
    float* wahp   = ws + 8503296;                  // 262,144 (8*64*512)
    float* ghhp   = ws + 8765440;                  // 1,048,576 (8*64*2048)
    float* bias2  = ws + 9814016;                  // 2,048
    u16*  fhi     = (u16*)(ws + 9816064);          // [9816064, 13027328)
    u16*  fcnw_h  = (u16*)(ws + 13027328);         // [13027328, 15587328)
    // aliases over dead producers:
    float* pbuf   = ws;                            // init partials (in fW16 region)
    float* mean_f = ws + 1048576;                  // after pbuf, still in fW16 region
    u16*  ihw_h   = (u16*)pre_x;                   // [4014080, 6111232) pre-split ih_w hi
    u16*  ihw_l   = (u16*)(ws + 6111232);          // [6111232, 8208384) (pre_x tail + Hall head, both dead)

    // init hidden state
    k_mean<<<64, 256, 0, stream>>>(features, mean_f);
    k_init_partial<<<dim3(16, 16), 256, 0, stream>>>(mean_f, iH_w, iC_w, pbuf);
    k_init_reduce<<<256, 256, 0, stream>>>(pbuf, iH_b, iC_b, h_cur, c_cur);

    // merged preprocessing: ih_w split, fcn_w hi, features hi, bias2
    k_prep<<<6117, 256, 0, stream>>>(ih_w, fcn_w, features, ih_b, hh_b,
                                     ihw_h, ihw_l, fcnw_h, fhi, bias2);

    // combined u_hs+fW GEMM (2-term): [3136 x 2560] over K=2048
    mfma_cat3<<<dim3(20, 25), 512, 0, stream>>>(fhi, U_w, U_b, ihw_h, ihw_l,
                                                uhs16, fW16, B * NN);
    // pre_x with fused embedding gather (overwrites dead ihw buffers)
    mfma_prex<<<dim3(16, 15), 512, 0, stream>>>(captions, emb, ih_w, bias2, pre_x);

    // recurrence
    k_hw8<<<dim3(40, 8), 256, 0, stream>>>(h_cur, W_w, W_b, hh_w, wahp, ghhp);
    for (int s = 0; s < TT; ++s) {
        k_fused6<<<dim3(64, 4), 512, 0, stream>>>(uhs16, A_w, A_b, wahp, ghhp, pre_x, fW16,
                                                  h_cur, c_cur, Hall_h, alphas, s);
        if (s < TT - 1)
            k_hw8<<<dim3(40, 8), 256, 0, stream>>>(h_cur, W_w, W_b, hh_w, wahp, ghhp);
    }

    // pure-bf16 output projection
    mfma_pre3<<<dim3(79, 15), 512, 0, stream>>>(Hall_h, fcnw_h, fcn_b,
                                                out, TT * B, VOC);
}